// Round 2
// baseline (25531.259 us; speedup 1.0000x reference)
//
#include <hip/hip_runtime.h>
#include <cstdint>
#include <cstddef>

#define NND 50000
#define NE  800000
#define DD  128
#define NG  500

// ---------------------------------------------------------------- input proj
__global__ __launch_bounds__(256) void inproj_kernel(
    const float* __restrict__ x, const float* __restrict__ W,
    const float* __restrict__ b, float* __restrict__ h)
{
    int t = blockIdx.x * 256 + threadIdx.x;      // t over N*128
    int i = t >> 7, d = t & 127;
    if (i >= NND) return;
    const float* xr = x + (size_t)i * 11;
    float acc = b[d];
#pragma unroll
    for (int k = 0; k < 11; ++k) acc += xr[k] * W[k * DD + d];
    h[(size_t)i * DD + d] = acc;
}

// ---------------------------------------------------------------- d2 = |pos_i - pos_j|^2
__global__ __launch_bounds__(256) void d2_kernel(
    const float* __restrict__ pos, const int* __restrict__ srcI,
    const int* __restrict__ dstI, float* __restrict__ d2)
{
    int e = blockIdx.x * 256 + threadIdx.x;
    if (e >= NE) return;
    int s = srcI[e], d = dstI[e];
    float dx = pos[d * 3 + 0] - pos[s * 3 + 0];
    float dy = pos[d * 3 + 1] - pos[s * 3 + 1];
    float dz = pos[d * 3 + 2] - pos[s * 3 + 2];
    d2[e] = dx * dx + dy * dy + dz * dz;
}

// ---------------------------------------------------------------- message MLP + scatter
__global__ __launch_bounds__(256, 2) void msg_kernel(
    const float* __restrict__ h, const int* __restrict__ srcI, const int* __restrict__ dstI,
    const float* __restrict__ ea, const float* __restrict__ d2,
    const float* __restrict__ W1, const float* __restrict__ b1,
    const float* __restrict__ W2, const float* __restrict__ b2,
    float* __restrict__ agg)
{
    __shared__ float tls[256][33];               // private per-thread chunk; 2-way bank alias = free
    int e = blockIdx.x * 256 + threadIdx.x;
    if (e >= NE) return;
    int is = srcI[e], id = dstI[e];
    const float4* hdp = (const float4*)(h + (size_t)id * DD);
    const float4* hsp = (const float4*)(h + (size_t)is * DD);
    float4 eav = ((const float4*)ea)[e];
    float  d2v = d2[e];

    float macc[DD];
#pragma unroll
    for (int d = 0; d < DD; ++d) macc[d] = b2[d];

    for (int c = 0; c < 4; ++c) {                // 4 chunks of 32 hidden units
        float tt[32];
        const float* b1c = b1 + c * 32;
#pragma unroll
        for (int j = 0; j < 32; ++j) tt[j] = b1c[j];
        const float* w1c = W1 + c * 32;

        for (int k4 = 0; k4 < 32; ++k4) {        // h[dst] -> rows 0..127
            float4 xv = hdp[k4];
#pragma unroll
            for (int jj = 0; jj < 4; ++jj) {
                float xx = (&xv.x)[jj];
                const float* wr = w1c + (k4 * 4 + jj) * DD;
#pragma unroll
                for (int d = 0; d < 32; ++d) tt[d] += xx * wr[d];
            }
        }
        for (int k4 = 0; k4 < 32; ++k4) {        // h[src] -> rows 128..255
            float4 xv = hsp[k4];
#pragma unroll
            for (int jj = 0; jj < 4; ++jj) {
                float xx = (&xv.x)[jj];
                const float* wr = w1c + (128 + k4 * 4 + jj) * DD;
#pragma unroll
                for (int d = 0; d < 32; ++d) tt[d] += xx * wr[d];
            }
        }
#pragma unroll
        for (int jj = 0; jj < 4; ++jj) {         // edge_attr -> rows 256..259
            float xx = (&eav.x)[jj];
            const float* wr = w1c + (256 + jj) * DD;
#pragma unroll
            for (int d = 0; d < 32; ++d) tt[d] += xx * wr[d];
        }
        {                                        // d2 -> row 260
            const float* wr = w1c + 260 * DD;
#pragma unroll
            for (int d = 0; d < 32; ++d) tt[d] += d2v * wr[d];
        }

#pragma unroll
        for (int j = 0; j < 32; ++j) tls[threadIdx.x][j] = tt[j];
        const float* w2c = W2 + (c * 32) * DD;
        for (int j = 0; j < 32; ++j) {
            float tv = fmaxf(tls[threadIdx.x][j], 0.0f);
            const float* wr = w2c + j * DD;
#pragma unroll
            for (int d = 0; d < DD; ++d) macc[d] += tv * wr[d];
        }
    }

    float* ag = agg + (size_t)id * DD;
#pragma unroll
    for (int d = 0; d < DD; ++d) unsafeAtomicAdd(ag + d, macc[d]);
}

// ---------------------------------------------------------------- node update MLP + residual + LN (in place)
__global__ __launch_bounds__(256, 2) void upd_kernel(
    float* __restrict__ h, const float* __restrict__ agg,
    const float* __restrict__ W1, const float* __restrict__ b1,
    const float* __restrict__ W2, const float* __restrict__ b2,
    const float* __restrict__ lng, const float* __restrict__ lnb)
{
    __shared__ float tls[256][33];
    int i = blockIdx.x * 256 + threadIdx.x;
    if (i >= NND) return;
    const float4* hp = (const float4*)(h + (size_t)i * DD);
    const float4* ap = (const float4*)(agg + (size_t)i * DD);

    float macc[DD];
#pragma unroll
    for (int d = 0; d < DD; ++d) macc[d] = b2[d];

    for (int c = 0; c < 4; ++c) {
        float tt[32];
        const float* b1c = b1 + c * 32;
#pragma unroll
        for (int j = 0; j < 32; ++j) tt[j] = b1c[j];
        const float* w1c = W1 + c * 32;

        for (int k4 = 0; k4 < 32; ++k4) {        // h -> rows 0..127
            float4 xv = hp[k4];
#pragma unroll
            for (int jj = 0; jj < 4; ++jj) {
                float xx = (&xv.x)[jj];
                const float* wr = w1c + (k4 * 4 + jj) * DD;
#pragma unroll
                for (int d = 0; d < 32; ++d) tt[d] += xx * wr[d];
            }
        }
        for (int k4 = 0; k4 < 32; ++k4) {        // agg -> rows 128..255
            float4 xv = ap[k4];
#pragma unroll
            for (int jj = 0; jj < 4; ++jj) {
                float xx = (&xv.x)[jj];
                const float* wr = w1c + (128 + k4 * 4 + jj) * DD;
#pragma unroll
                for (int d = 0; d < 32; ++d) tt[d] += xx * wr[d];
            }
        }

#pragma unroll
        for (int j = 0; j < 32; ++j) tls[threadIdx.x][j] = tt[j];
        const float* w2c = W2 + (c * 32) * DD;
        for (int j = 0; j < 32; ++j) {
            float tv = fmaxf(tls[threadIdx.x][j], 0.0f);
            const float* wr = w2c + j * DD;
#pragma unroll
            for (int d = 0; d < DD; ++d) macc[d] += tv * wr[d];
        }
    }

    // residual + LayerNorm, fully in-register
#pragma unroll
    for (int k4 = 0; k4 < 32; ++k4) {
        float4 xv = hp[k4];
        macc[k4 * 4 + 0] += xv.x; macc[k4 * 4 + 1] += xv.y;
        macc[k4 * 4 + 2] += xv.z; macc[k4 * 4 + 3] += xv.w;
    }
    float mean = 0.f;
#pragma unroll
    for (int d = 0; d < DD; ++d) mean += macc[d];
    mean *= (1.0f / DD);
    float var = 0.f;
#pragma unroll
    for (int d = 0; d < DD; ++d) { float dv = macc[d] - mean; var += dv * dv; }
    var *= (1.0f / DD);
    float inv = 1.0f / sqrtf(var + 1e-5f);
    float* ho = h + (size_t)i * DD;
#pragma unroll
    for (int d = 0; d < DD; ++d) ho[d] = (macc[d] - mean) * inv * lng[d] + lnb[d];
}

// ---------------------------------------------------------------- pooling
__global__ __launch_bounds__(256) void cnt_kernel(
    const int* __restrict__ batch, float* __restrict__ cnt)
{
    int i = blockIdx.x * 256 + threadIdx.x;
    if (i >= NND) return;
    unsafeAtomicAdd(&cnt[batch[i]], 1.0f);
}

__global__ __launch_bounds__(256) void pool_kernel(
    const float* __restrict__ h, const int* __restrict__ batch, float* __restrict__ hs)
{
    int t = blockIdx.x * 256 + threadIdx.x;
    int i = t >> 7, d = t & 127;
    if (i >= NND) return;
    unsafeAtomicAdd(&hs[batch[i] * DD + d], h[(size_t)i * DD + d]);
}

// ---------------------------------------------------------------- decoder (one block per graph*head)
__device__ __forceinline__ float softplus_stable(float y) {
    return fmaxf(y, 0.0f) + log1pf(expf(-fabsf(y)));
}

__global__ __launch_bounds__(256) void dec_kernel(
    const float* __restrict__ hs, const float* __restrict__ cnt,
    const float* __restrict__ W1, const float* __restrict__ b1,
    const float* __restrict__ lng, const float* __restrict__ lnb,
    const float* __restrict__ W2, const float* __restrict__ b2,
    const float* __restrict__ W3, const float* __restrict__ b3,
    float* __restrict__ out)
{
    int g  = blockIdx.x >> 1;
    int hd = blockIdx.x & 1;
    int t  = threadIdx.x;
    __shared__ float hg[DD];
    __shared__ float sA[256];
    __shared__ float red[256];

    if (t < DD) {
        float c = fmaxf(cnt[g], 1.0f);
        hg[t] = hs[g * DD + t] / c;
    }
    __syncthreads();

    const float* w1 = W1 + hd * DD * 256;
    float acc = b1[hd * 256 + t];
#pragma unroll 8
    for (int k = 0; k < DD; ++k) acc += hg[k] * w1[k * 256 + t];

    // LayerNorm over 256
    red[t] = acc; __syncthreads();
    for (int s = 128; s > 0; s >>= 1) { if (t < s) red[t] += red[t + s]; __syncthreads(); }
    float mean = red[0] * (1.0f / 256.0f);
    __syncthreads();
    float dv = acc - mean;
    red[t] = dv * dv; __syncthreads();
    for (int s = 128; s > 0; s >>= 1) { if (t < s) red[t] += red[t + s]; __syncthreads(); }
    float var = red[0] * (1.0f / 256.0f);
    float inv = 1.0f / sqrtf(var + 1e-5f);
    float z1 = dv * inv * lng[hd * 256 + t] + lnb[hd * 256 + t];
    z1 = softplus_stable(2.0f * z1) * 0.5f;
    __syncthreads();
    sA[t] = z1; __syncthreads();

    const float* w2 = W2 + hd * 256 * 256;
    float acc2 = b2[hd * 256 + t];
#pragma unroll 8
    for (int k = 0; k < 256; ++k) acc2 += sA[k] * w2[k * 256 + t];
    float z2 = softplus_stable(2.0f * acc2) * 0.5f;
    __syncthreads();
    sA[t] = z2; __syncthreads();

    const float* w3 = W3 + hd * 256 * 300;
    for (int s = t; s < 300; s += 256) {
        float acc3 = b3[hd * 300 + s];
#pragma unroll 8
        for (int k = 0; k < 256; ++k) acc3 += sA[k] * w3[k * 300 + s];
        out[g * 600 + hd * 300 + s] = softplus_stable(acc3);
    }
}

// ---------------------------------------------------------------- launch
extern "C" void kernel_launch(void* const* d_in, const int* in_sizes, int n_in,
                              void* d_out, int out_size, void* d_ws, size_t ws_size,
                              hipStream_t stream)
{
    const float* x     = (const float*)d_in[0];
    const float* pos   = (const float*)d_in[1];
    const float* eattr = (const float*)d_in[2];
    const int*   eidx  = (const int*)d_in[3];
    const int*   batch = (const int*)d_in[4];
    const float* W_in  = (const float*)d_in[5];
    const float* b_in  = (const float*)d_in[6];
    const float* msgW1 = (const float*)d_in[7];
    const float* msgb1 = (const float*)d_in[8];
    const float* msgW2 = (const float*)d_in[9];
    const float* msgb2 = (const float*)d_in[10];
    const float* updW1 = (const float*)d_in[11];
    const float* updb1 = (const float*)d_in[12];
    const float* updW2 = (const float*)d_in[13];
    const float* updb2 = (const float*)d_in[14];
    const float* lng   = (const float*)d_in[15];
    const float* lnb   = (const float*)d_in[16];
    const float* dW1   = (const float*)d_in[17];
    const float* db1   = (const float*)d_in[18];
    const float* dlng  = (const float*)d_in[19];
    const float* dlnb  = (const float*)d_in[20];
    const float* dW2   = (const float*)d_in[21];
    const float* db2   = (const float*)d_in[22];
    const float* dW3   = (const float*)d_in[23];
    const float* db3   = (const float*)d_in[24];

    float* ws  = (float*)d_ws;
    float* h   = ws;                  // N*128
    float* agg = ws + 6400000;        // N*128
    float* d2  = ws + 12800000;       // E
    float* hsg = ws + 13600000;       // G*128
    float* cnt = ws + 13664000;       // G

    const int* srcI = eidx;
    const int* dstI = eidx + NE;

    inproj_kernel<<<25000, 256, 0, stream>>>(x, W_in, b_in, h);
    d2_kernel<<<3125, 256, 0, stream>>>(pos, srcI, dstI, d2);

    for (int l = 0; l < 4; ++l) {
        hipMemsetAsync(agg, 0, 6400000 * sizeof(float), stream);
        msg_kernel<<<3125, 256, 0, stream>>>(h, srcI, dstI, eattr, d2,
            msgW1 + (size_t)l * 261 * 128, msgb1 + l * 128,
            msgW2 + (size_t)l * 128 * 128, msgb2 + l * 128, agg);
        upd_kernel<<<196, 256, 0, stream>>>(h, agg,
            updW1 + (size_t)l * 256 * 128, updb1 + l * 128,
            updW2 + (size_t)l * 128 * 128, updb2 + l * 128,
            lng + l * 128, lnb + l * 128);
    }

    hipMemsetAsync(hsg, 0, 64500 * sizeof(float), stream);
    cnt_kernel<<<196, 256, 0, stream>>>(batch, cnt);
    pool_kernel<<<25000, 256, 0, stream>>>(h, batch, hsg);
    dec_kernel<<<1000, 256, 0, stream>>>(hsg, cnt, dW1, db1, dlng, dlnb,
                                         dW2, db2, dW3, db3, (float*)d_out);
}

// Round 5
// 12088.328 us; speedup vs baseline: 2.1121x; 2.1121x over previous
//
#include <hip/hip_runtime.h>
#include <cstdint>
#include <cstddef>

#define NND 50000
#define NE  800000
#define DD  128
#define NG  500
#define TT  64    // tile rows (edges/nodes) per block

// Thread micro-tile mapping used by all GEMM-style kernels:
//   tx = tid & 15  -> 4 rows   (tx*4 .. tx*4+3)   of the 64-row tile
//   ty = tid >> 4  -> 8 cols   (ty*8 .. ty*8+7)   of the 128-col output
// acc[4][8] in VGPRs.

// ---------------------------------------------------------------- input proj
__global__ __launch_bounds__(256) void inproj_kernel(
    const float* __restrict__ x, const float* __restrict__ W,
    const float* __restrict__ b, float* __restrict__ h)
{
    int t = blockIdx.x * 256 + threadIdx.x;
    int i = t >> 7, d = t & 127;
    if (i >= NND) return;
    const float* xr = x + (size_t)i * 11;
    float acc = b[d];
#pragma unroll
    for (int k = 0; k < 11; ++k) acc += xr[k] * W[k * DD + d];
    h[(size_t)i * DD + d] = acc;
}

// ---------------------------------------------------------------- d2
__global__ __launch_bounds__(256) void d2_kernel(
    const float* __restrict__ pos, const int* __restrict__ srcI,
    const int* __restrict__ dstI, float* __restrict__ d2)
{
    int e = blockIdx.x * 256 + threadIdx.x;
    if (e >= NE) return;
    int s = srcI[e], d = dstI[e];
    float dx = pos[d * 3 + 0] - pos[s * 3 + 0];
    float dy = pos[d * 3 + 1] - pos[s * 3 + 1];
    float dz = pos[d * 3 + 2] - pos[s * 3 + 2];
    d2[e] = dx * dx + dy * dy + dz * dz;
}

// ---------------------------------------------------------------- node projections P = h @ W1a / W1b
// grid (ceil(N/64), 2); mat 0 -> W1 rows 0..127 (dst part), mat 1 -> rows 128..255 (src part)
__global__ __launch_bounds__(256, 4) void proj_kernel(
    const float* __restrict__ h, const float* __restrict__ W1, float* __restrict__ P)
{
    __shared__ __align__(16) float A[32][TT];   // 8 KB, transposed [k][row]
    __shared__ __align__(16) float B[32][DD];   // 16 KB
    int i0 = blockIdx.x * TT;
    int mat = blockIdx.y;
    const float* W = W1 + (size_t)mat * 128 * DD;
    float* out = P + (size_t)mat * NND * DD;
    int t = threadIdx.x;
    int tx = t & 15, ty = t >> 4;
    int e = t & 63, q = t >> 6;
    int node = i0 + e; if (node >= NND) node = NND - 1;   // clamped read, guarded store
    const float* hrow = h + (size_t)node * DD;

    float acc[4][8];
#pragma unroll
    for (int i = 0; i < 4; ++i)
#pragma unroll
        for (int j = 0; j < 8; ++j) acc[i][j] = 0.0f;

    for (int c = 0; c < 4; ++c) {
        __syncthreads();
        float4 v0 = *(const float4*)(hrow + c * 32 + q * 8);
        float4 v1 = *(const float4*)(hrow + c * 32 + q * 8 + 4);
#pragma unroll
        for (int j = 0; j < 4; ++j) A[q * 8 + j][e]     = (&v0.x)[j];
#pragma unroll
        for (int j = 0; j < 4; ++j) A[q * 8 + 4 + j][e] = (&v1.x)[j];
        const float4* srcp = (const float4*)(W + (size_t)(c * 32) * DD);
        float4* dstp = (float4*)&B[0][0];
#pragma unroll
        for (int r = 0; r < 4; ++r) dstp[t + r * 256] = srcp[t + r * 256];
        __syncthreads();
#pragma unroll 4
        for (int k = 0; k < 32; ++k) {
            float4 a  = *(const float4*)&A[k][tx * 4];
            float4 b0 = *(const float4*)&B[k][ty * 8];
            float4 b1 = *(const float4*)&B[k][ty * 8 + 4];
            float av[4] = {a.x, a.y, a.z, a.w};
            float bv[8] = {b0.x, b0.y, b0.z, b0.w, b1.x, b1.y, b1.z, b1.w};
#pragma unroll
            for (int i = 0; i < 4; ++i)
#pragma unroll
                for (int j = 0; j < 8; ++j) acc[i][j] += av[i] * bv[j];
        }
    }
#pragma unroll
    for (int i = 0; i < 4; ++i) {
        int r = i0 + tx * 4 + i;
        if (r < NND) {
            float4 o0 = {acc[i][0], acc[i][1], acc[i][2], acc[i][3]};
            float4 o1 = {acc[i][4], acc[i][5], acc[i][6], acc[i][7]};
            *(float4*)(out + (size_t)r * DD + ty * 8)     = o0;
            *(float4*)(out + (size_t)r * DD + ty * 8 + 4) = o1;
        }
    }
}

// ---------------------------------------------------------------- message (factored): T = relu(Pd[dst]+Ps[src]+ea@Wc+b1); M = T@W2+b2; scatter
__global__ __launch_bounds__(256, 3) void msgf_kernel(
    const float* __restrict__ P, const int* __restrict__ srcI, const int* __restrict__ dstI,
    const float* __restrict__ ea, const float* __restrict__ d2,
    const float* __restrict__ W1tail,   // W1 rows 256..260, [5][128]
    const float* __restrict__ b1, const float* __restrict__ W2, const float* __restrict__ b2,
    float* __restrict__ agg)
{
    __shared__ __align__(16) float T[DD][TT];   // 32 KB, [hidden][edge]
    __shared__ __align__(16) float B[32][DD];   // 16 KB
    __shared__ __align__(16) float Wc[5][DD];   // 2.5 KB
    int t = threadIdx.x;
    int e0 = blockIdx.x * TT;
    int tx = t & 15, ty = t >> 4;

    if (t < 160) ((float4*)&Wc[0][0])[t] = ((const float4*)W1tail)[t];
    __syncthreads();

    float4 b1a = *(const float4*)(b1 + ty * 8);
    float4 b1b = *(const float4*)(b1 + ty * 8 + 4);
    float b1v[8] = {b1a.x, b1a.y, b1a.z, b1a.w, b1b.x, b1b.y, b1b.z, b1b.w};

    const float* Pd = P;
    const float* Ps = P + (size_t)NND * DD;
    int dcache[4];
#pragma unroll
    for (int i = 0; i < 4; ++i) {
        int e  = tx * 4 + i;
        int ds = dstI[e0 + e];
        int sr = srcI[e0 + e];
        dcache[i] = ds;
        const float* pd = Pd + (size_t)ds * DD + ty * 8;
        const float* ps = Ps + (size_t)sr * DD + ty * 8;
        float4 p0 = *(const float4*)pd;
        float4 p1 = *(const float4*)(pd + 4);
        float4 q0 = *(const float4*)ps;
        float4 q1 = *(const float4*)(ps + 4);
        float tv[8] = {p0.x + q0.x, p0.y + q0.y, p0.z + q0.z, p0.w + q0.w,
                       p1.x + q1.x, p1.y + q1.y, p1.z + q1.z, p1.w + q1.w};
#pragma unroll
        for (int j = 0; j < 8; ++j) tv[j] += b1v[j];
        float4 av = ((const float4*)ea)[e0 + e];
        float ev[5] = {av.x, av.y, av.z, av.w, d2[e0 + e]};
#pragma unroll
        for (int qf = 0; qf < 5; ++qf) {
            float xx = ev[qf];
#pragma unroll
            for (int j = 0; j < 8; ++j) tv[j] += xx * Wc[qf][ty * 8 + j];
        }
#pragma unroll
        for (int j = 0; j < 8; ++j) T[ty * 8 + j][e] = fmaxf(tv[j], 0.0f);
    }

    float4 b2a = *(const float4*)(b2 + ty * 8);
    float4 b2b = *(const float4*)(b2 + ty * 8 + 4);
    float acc[4][8];
#pragma unroll
    for (int i = 0; i < 4; ++i) {
        acc[i][0] = b2a.x; acc[i][1] = b2a.y; acc[i][2] = b2a.z; acc[i][3] = b2a.w;
        acc[i][4] = b2b.x; acc[i][5] = b2b.y; acc[i][6] = b2b.z; acc[i][7] = b2b.w;
    }

    for (int c = 0; c < 4; ++c) {
        __syncthreads();                       // first iter: covers T writes; later: B reads done
        const float4* srcp = (const float4*)(W2 + (size_t)(c * 32) * DD);
        float4* dstp = (float4*)&B[0][0];
#pragma unroll
        for (int r = 0; r < 4; ++r) dstp[t + r * 256] = srcp[t + r * 256];
        __syncthreads();
#pragma unroll 4
        for (int k = 0; k < 32; ++k) {
            float4 a  = *(const float4*)&T[c * 32 + k][tx * 4];
            float4 b0 = *(const float4*)&B[k][ty * 8];
            float4 b1f = *(const float4*)&B[k][ty * 8 + 4];
            float av[4] = {a.x, a.y, a.z, a.w};
            float bv[8] = {b0.x, b0.y, b0.z, b0.w, b1f.x, b1f.y, b1f.z, b1f.w};
#pragma unroll
            for (int i = 0; i < 4; ++i)
#pragma unroll
                for (int j = 0; j < 8; ++j) acc[i][j] += av[i] * bv[j];
        }
    }

#pragma unroll
    for (int i = 0; i < 4; ++i) {
        float* ag = agg + (size_t)dcache[i] * DD + ty * 8;
#pragma unroll
        for (int j = 0; j < 8; ++j) unsafeAtomicAdd(ag + j, acc[i][j]);
    }
}

// ---------------------------------------------------------------- message (unfactored fallback, K=261 GEMM)
__global__ __launch_bounds__(256, 2) void msgu_kernel(
    const float* __restrict__ h, const int* __restrict__ srcI, const int* __restrict__ dstI,
    const float* __restrict__ ea, const float* __restrict__ d2,
    const float* __restrict__ W1, const float* __restrict__ b1,
    const float* __restrict__ W2, const float* __restrict__ b2,
    float* __restrict__ agg)
{
    __shared__ __align__(16) float A[32][TT];
    __shared__ __align__(16) float T[DD][TT];
    __shared__ __align__(16) float B[32][DD];
    int t = threadIdx.x;
    int e0 = blockIdx.x * TT;
    int tx = t & 15, ty = t >> 4;
    int e = t & 63, q = t >> 6;
    int dn = dstI[e0 + e], sn = srcI[e0 + e];

    float4 b1a = *(const float4*)(b1 + ty * 8);
    float4 b1b = *(const float4*)(b1 + ty * 8 + 4);
    float acc[4][8];
#pragma unroll
    for (int i = 0; i < 4; ++i) {
        acc[i][0] = b1a.x; acc[i][1] = b1a.y; acc[i][2] = b1a.z; acc[i][3] = b1a.w;
        acc[i][4] = b1b.x; acc[i][5] = b1b.y; acc[i][6] = b1b.z; acc[i][7] = b1b.w;
    }

    for (int c = 0; c < 9; ++c) {
        int kmax = (c == 8) ? 5 : 32;
        __syncthreads();
        if (c < 8) {
            const float* row = h + (size_t)((c < 4) ? dn : sn) * DD + (c & 3) * 32;
            float4 v0 = *(const float4*)(row + q * 8);
            float4 v1 = *(const float4*)(row + q * 8 + 4);
#pragma unroll
            for (int j = 0; j < 4; ++j) A[q * 8 + j][e]     = (&v0.x)[j];
#pragma unroll
            for (int j = 0; j < 4; ++j) A[q * 8 + 4 + j][e] = (&v1.x)[j];
        } else if (t < TT) {
            float4 av = ((const float4*)ea)[e0 + t];
            A[0][t] = av.x; A[1][t] = av.y; A[2][t] = av.z; A[3][t] = av.w;
            A[4][t] = d2[e0 + t];
        }
        const float4* srcp = (const float4*)(W1 + (size_t)(c * 32) * DD);
        float4* dstp = (float4*)&B[0][0];
        if (c < 8) {
#pragma unroll
            for (int r = 0; r < 4; ++r) dstp[t + r * 256] = srcp[t + r * 256];
        } else if (t < 160) {
            dstp[t] = srcp[t];
        }
        __syncthreads();
        for (int k = 0; k < kmax; ++k) {
            float4 a  = *(const float4*)&A[k][tx * 4];
            float4 b0 = *(const float4*)&B[k][ty * 8];
            float4 b1f = *(const float4*)&B[k][ty * 8 + 4];
            float av[4] = {a.x, a.y, a.z, a.w};
            float bv[8] = {b0.x, b0.y, b0.z, b0.w, b1f.x, b1f.y, b1f.z, b1f.w};
#pragma unroll
            for (int i = 0; i < 4; ++i)
#pragma unroll
                for (int j = 0; j < 8; ++j) acc[i][j] += av[i] * bv[j];
        }
    }

#pragma unroll
    for (int i = 0; i < 4; ++i)
#pragma unroll
        for (int j = 0; j < 8; ++j) T[ty * 8 + j][tx * 4 + i] = fmaxf(acc[i][j], 0.0f);

    float4 b2a = *(const float4*)(b2 + ty * 8);
    float4 b2b = *(const float4*)(b2 + ty * 8 + 4);
#pragma unroll
    for (int i = 0; i < 4; ++i) {
        acc[i][0] = b2a.x; acc[i][1] = b2a.y; acc[i][2] = b2a.z; acc[i][3] = b2a.w;
        acc[i][4] = b2b.x; acc[i][5] = b2b.y; acc[i][6] = b2b.z; acc[i][7] = b2b.w;
    }
    for (int c = 0; c < 4; ++c) {
        __syncthreads();
        const float4* srcp = (const float4*)(W2 + (size_t)(c * 32) * DD);
        float4* dstp = (float4*)&B[0][0];
#pragma unroll
        for (int r = 0; r < 4; ++r) dstp[t + r * 256] = srcp[t + r * 256];
        __syncthreads();
#pragma unroll 4
        for (int k = 0; k < 32; ++k) {
            float4 a  = *(const float4*)&T[c * 32 + k][tx * 4];
            float4 b0 = *(const float4*)&B[k][ty * 8];
            float4 b1f = *(const float4*)&B[k][ty * 8 + 4];
            float av[4] = {a.x, a.y, a.z, a.w};
            float bv[8] = {b0.x, b0.y, b0.z, b0.w, b1f.x, b1f.y, b1f.z, b1f.w};
#pragma unroll
            for (int i = 0; i < 4; ++i)
#pragma unroll
                for (int j = 0; j < 8; ++j) acc[i][j] += av[i] * bv[j];
        }
    }
#pragma unroll
    for (int i = 0; i < 4; ++i) {
        int d = dstI[e0 + tx * 4 + i];
        float* ag = agg + (size_t)d * DD + ty * 8;
#pragma unroll
        for (int j = 0; j < 8; ++j) unsafeAtomicAdd(ag + j, acc[i][j]);
    }
}

// ---------------------------------------------------------------- node update: GEMM(K=384) + residual + LN
__global__ __launch_bounds__(256, 2) void upd_kernel(
    float* __restrict__ h, const float* __restrict__ agg,
    const float* __restrict__ W1, const float* __restrict__ b1,
    const float* __restrict__ W2, const float* __restrict__ b2,
    const float* __restrict__ lng, const float* __restrict__ lnb)
{
    __shared__ __align__(16) float A[32][TT];
    __shared__ __align__(16) float T[DD][TT];
    __shared__ __align__(16) float B[32][DD];
    int t = threadIdx.x;
    int i0 = blockIdx.x * TT;
    int tx = t & 15, ty = t >> 4;
    int e = t & 63, q = t >> 6;
    int node = i0 + e; int nclamp = (node < NND) ? node : (NND - 1);

    float4 b1a = *(const float4*)(b1 + ty * 8);
    float4 b1b = *(const float4*)(b1 + ty * 8 + 4);
    float acc[4][8];
#pragma unroll
    for (int i = 0; i < 4; ++i) {
        acc[i][0] = b1a.x; acc[i][1] = b1a.y; acc[i][2] = b1a.z; acc[i][3] = b1a.w;
        acc[i][4] = b1b.x; acc[i][5] = b1b.y; acc[i][6] = b1b.z; acc[i][7] = b1b.w;
    }

    for (int c = 0; c < 8; ++c) {
        __syncthreads();
        const float* row = ((c < 4) ? (h + (size_t)nclamp * DD + c * 32)
                                    : (agg + (size_t)nclamp * DD + (c - 4) * 32));
        float4 v0 = *(const float4*)(row + q * 8);
        float4 v1 = *(const float4*)(row + q * 8 + 4);
#pragma unroll
        for (int j = 0; j < 4; ++j) A[q * 8 + j][e]     = (&v0.x)[j];
#pragma unroll
        for (int j = 0; j < 4; ++j) A[q * 8 + 4 + j][e] = (&v1.x)[j];
        const float4* srcp = (const float4*)(W1 + (size_t)(c * 32) * DD);
        float4* dstp = (float4*)&B[0][0];
#pragma unroll
        for (int r = 0; r < 4; ++r) dstp[t + r * 256] = srcp[t + r * 256];
        __syncthreads();
#pragma unroll 4
        for (int k = 0; k < 32; ++k) {
            float4 a  = *(const float4*)&A[k][tx * 4];
            float4 b0 = *(const float4*)&B[k][ty * 8];
            float4 b1f = *(const float4*)&B[k][ty * 8 + 4];
            float av[4] = {a.x, a.y, a.z, a.w};
            float bv[8] = {b0.x, b0.y, b0.z, b0.w, b1f.x, b1f.y, b1f.z, b1f.w};
#pragma unroll
            for (int i = 0; i < 4; ++i)
#pragma unroll
                for (int j = 0; j < 8; ++j) acc[i][j] += av[i] * bv[j];
        }
    }

#pragma unroll
    for (int i = 0; i < 4; ++i)
#pragma unroll
        for (int j = 0; j < 8; ++j) T[ty * 8 + j][tx * 4 + i] = fmaxf(acc[i][j], 0.0f);

    float4 b2a = *(const float4*)(b2 + ty * 8);
    float4 b2b = *(const float4*)(b2 + ty * 8 + 4);
#pragma unroll
    for (int i = 0; i < 4; ++i) {
        acc[i][0] = b2a.x; acc[i][1] = b2a.y; acc[i][2] = b2a.z; acc[i][3] = b2a.w;
        acc[i][4] = b2b.x; acc[i][5] = b2b.y; acc[i][6] = b2b.z; acc[i][7] = b2b.w;
    }
    for (int c = 0; c < 4; ++c) {
        __syncthreads();
        const float4* srcp = (const float4*)(W2 + (size_t)(c * 32) * DD);
        float4* dstp = (float4*)&B[0][0];
#pragma unroll
        for (int r = 0; r < 4; ++r) dstp[t + r * 256] = srcp[t + r * 256];
        __syncthreads();
#pragma unroll 4
        for (int k = 0; k < 32; ++k) {
            float4 a  = *(const float4*)&T[c * 32 + k][tx * 4];
            float4 b0 = *(const float4*)&B[k][ty * 8];
            float4 b1f = *(const float4*)&B[k][ty * 8 + 4];
            float av[4] = {a.x, a.y, a.z, a.w};
            float bv[8] = {b0.x, b0.y, b0.z, b0.w, b1f.x, b1f.y, b1f.z, b1f.w};
#pragma unroll
            for (int i = 0; i < 4; ++i)
#pragma unroll
                for (int j = 0; j < 8; ++j) acc[i][j] += av[i] * bv[j];
        }
    }

    __syncthreads();   // all T reads done; reuse T to stage M = h_upd
#pragma unroll
    for (int i = 0; i < 4; ++i)
#pragma unroll
        for (int j = 0; j < 8; ++j) T[ty * 8 + j][tx * 4 + i] = acc[i][j];
    __syncthreads();

    if (t < TT) {
        int nd = i0 + t;
        if (nd < NND) {
            float* hrow = h + (size_t)nd * DD;
            float sum = 0.0f;
            for (int o = 0; o < DD; ++o) sum += T[o][t] + hrow[o];
            float mean = sum * (1.0f / DD);
            float var = 0.0f;
            for (int o = 0; o < DD; ++o) {
                float xv = T[o][t] + hrow[o] - mean;
                var += xv * xv;
            }
            var *= (1.0f / DD);
            float inv = 1.0f / sqrtf(var + 1e-5f);
            for (int o = 0; o < DD; ++o) {
                float xv = T[o][t] + hrow[o];
                hrow[o] = (xv - mean) * inv * lng[o] + lnb[o];
            }
        }
    }
}

// ---------------------------------------------------------------- pooling
__global__ __launch_bounds__(256) void cnt_kernel(
    const int* __restrict__ batch, float* __restrict__ cnt)
{
    int i = blockIdx.x * 256 + threadIdx.x;
    if (i >= NND) return;
    unsafeAtomicAdd(&cnt[batch[i]], 1.0f);
}

__global__ __launch_bounds__(256) void pool_kernel(
    const float* __restrict__ h, const int* __restrict__ batch, float* __restrict__ hs)
{
    int t = blockIdx.x * 256 + threadIdx.x;
    int i = t >> 7, d = t & 127;
    if (i >= NND) return;
    unsafeAtomicAdd(&hs[batch[i] * DD + d], h[(size_t)i * DD + d]);
}

// ---------------------------------------------------------------- decoder
__device__ __forceinline__ float softplus_stable(float y) {
    return fmaxf(y, 0.0f) + log1pf(expf(-fabsf(y)));
}

__global__ __launch_bounds__(256) void dec_kernel(
    const float* __restrict__ hs, const float* __restrict__ cnt,
    const float* __restrict__ W1, const float* __restrict__ b1,
    const float* __restrict__ lng, const float* __restrict__ lnb,
    const float* __restrict__ W2, const float* __restrict__ b2,
    const float* __restrict__ W3, const float* __restrict__ b3,
    float* __restrict__ out)
{
    int g  = blockIdx.x >> 1;
    int hd = blockIdx.x & 1;
    int t  = threadIdx.x;
    __shared__ float hg[DD];
    __shared__ float sA[256];
    __shared__ float red[256];

    if (t < DD) {
        float c = fmaxf(cnt[g], 1.0f);
        hg[t] = hs[g * DD + t] / c;
    }
    __syncthreads();

    const float* w1 = W1 + hd * DD * 256;
    float acc = b1[hd * 256 + t];
#pragma unroll 8
    for (int k = 0; k < DD; ++k) acc += hg[k] * w1[k * 256 + t];

    red[t] = acc; __syncthreads();
    for (int s = 128; s > 0; s >>= 1) { if (t < s) red[t] += red[t + s]; __syncthreads(); }
    float mean = red[0] * (1.0f / 256.0f);
    __syncthreads();
    float dv = acc - mean;
    red[t] = dv * dv; __syncthreads();
    for (int s = 128; s > 0; s >>= 1) { if (t < s) red[t] += red[t + s]; __syncthreads(); }
    float var = red[0] * (1.0f / 256.0f);
    float inv = 1.0f / sqrtf(var + 1e-5f);
    float z1 = dv * inv * lng[hd * 256 + t] + lnb[hd * 256 + t];
    z1 = softplus_stable(2.0f * z1) * 0.5f;
    __syncthreads();
    sA[t] = z1; __syncthreads();

    const float* w2 = W2 + hd * 256 * 256;
    float acc2 = b2[hd * 256 + t];
#pragma unroll 8
    for (int k = 0; k < 256; ++k) acc2 += sA[k] * w2[k * 256 + t];
    float z2 = softplus_stable(2.0f * acc2) * 0.5f;
    __syncthreads();
    sA[t] = z2; __syncthreads();

    const float* w3 = W3 + hd * 256 * 300;
    for (int s = t; s < 300; s += 256) {
        float acc3 = b3[hd * 300 + s];
#pragma unroll 8
        for (int k = 0; k < 256; ++k) acc3 += sA[k] * w3[k * 300 + s];
        out[g * 600 + hd * 300 + s] = softplus_stable(acc3);
    }
}

// ---------------------------------------------------------------- launch
extern "C" void kernel_launch(void* const* d_in, const int* in_sizes, int n_in,
                              void* d_out, int out_size, void* d_ws, size_t ws_size,
                              hipStream_t stream)
{
    const float* x     = (const float*)d_in[0];
    const float* pos   = (const float*)d_in[1];
    const float* eattr = (const float*)d_in[2];
    const int*   eidx  = (const int*)d_in[3];
    const int*   batch = (const int*)d_in[4];
    const float* W_in  = (const float*)d_in[5];
    const float* b_in  = (const float*)d_in[6];
    const float* msgW1 = (const float*)d_in[7];
    const float* msgb1 = (const float*)d_in[8];
    const float* msgW2 = (const float*)d_in[9];
    const float* msgb2 = (const float*)d_in[10];
    const float* updW1 = (const float*)d_in[11];
    const float* updb1 = (const float*)d_in[12];
    const float* updW2 = (const float*)d_in[13];
    const float* updb2 = (const float*)d_in[14];
    const float* lng   = (const float*)d_in[15];
    const float* lnb   = (const float*)d_in[16];
    const float* dW1   = (const float*)d_in[17];
    const float* db1   = (const float*)d_in[18];
    const float* dlng  = (const float*)d_in[19];
    const float* dlnb  = (const float*)d_in[20];
    const float* dW2   = (const float*)d_in[21];
    const float* db2   = (const float*)d_in[22];
    const float* dW3   = (const float*)d_in[23];
    const float* db3   = (const float*)d_in[24];

    float* ws  = (float*)d_ws;
    float* h   = ws;                  // N*128
    float* agg = ws + 6400000;        // N*128
    float* d2  = ws + 12800000;       // E
    float* hsg = ws + 13600000;       // G*128
    float* cnt = ws + 13664000;       // G
    float* P   = ws + 13700000;       // 2*N*128 (factored path only)

    const size_t need_bytes = (size_t)(13700000 + 2 * NND * DD) * 4;
    const bool factored = (ws_size >= need_bytes);

    const int* srcI = eidx;
    const int* dstI = eidx + NE;

    inproj_kernel<<<25000, 256, 0, stream>>>(x, W_in, b_in, h);
    d2_kernel<<<3125, 256, 0, stream>>>(pos, srcI, dstI, d2);

    const int nblk_nodes = (NND + TT - 1) / TT;   // 782
    const int nblk_edges = NE / TT;               // 12500

    for (int l = 0; l < 4; ++l) {
        const float* W1l = msgW1 + (size_t)l * 261 * 128;
        hipMemsetAsync(agg, 0, 6400000 * sizeof(float), stream);
        if (factored) {
            proj_kernel<<<dim3(nblk_nodes, 2), 256, 0, stream>>>(h, W1l, P);
            msgf_kernel<<<nblk_edges, 256, 0, stream>>>(P, srcI, dstI, eattr, d2,
                W1l + 256 * 128, msgb1 + l * 128,
                msgW2 + (size_t)l * 128 * 128, msgb2 + l * 128, agg);
        } else {
            msgu_kernel<<<nblk_edges, 256, 0, stream>>>(h, srcI, dstI, eattr, d2,
                W1l, msgb1 + l * 128,
                msgW2 + (size_t)l * 128 * 128, msgb2 + l * 128, agg);
        }
        upd_kernel<<<nblk_nodes, 256, 0, stream>>>(h, agg,
            updW1 + (size_t)l * 256 * 128, updb1 + l * 128,
            updW2 + (size_t)l * 128 * 128, updb2 + l * 128,
            lng + l * 128, lnb + l * 128);
    }

    hipMemsetAsync(hsg, 0, 64500 * sizeof(float), stream);
    cnt_kernel<<<196, 256, 0, stream>>>(batch, cnt);
    pool_kernel<<<25000, 256, 0, stream>>>(h, batch, hsg);
    dec_kernel<<<1000, 256, 0, stream>>>(hsg, cnt, dW1, db1, dlng, dlnb,
                                         dW2, db2, dW3, db3, (float*)d_out);
}

// Round 6
// 7196.922 us; speedup vs baseline: 3.5475x; 1.6797x over previous
//
#include <hip/hip_runtime.h>
#include <cstdint>
#include <cstddef>

#define NND 50000
#define NE  800000
#define DD  128
#define NG  500
#define TT  64      // tile rows (edges/nodes) per block
#define NHB 50176   // hist size, padded to 196*256 exactly

// Thread micro-tile mapping (all GEMM-style kernels):
//   tx = tid & 15 -> 4 rows of the 64-row tile ; ty = tid >> 4 -> 8 cols of 128
// acc[4][8] in VGPRs.

// ---------------------------------------------------------------- input proj
__global__ __launch_bounds__(256) void inproj_kernel(
    const float* __restrict__ x, const float* __restrict__ W,
    const float* __restrict__ b, float* __restrict__ h)
{
    int t = blockIdx.x * 256 + threadIdx.x;
    int i = t >> 7, d = t & 127;
    if (i >= NND) return;
    const float* xr = x + (size_t)i * 11;
    float acc = b[d];
#pragma unroll
    for (int k = 0; k < 11; ++k) acc += xr[k] * W[k * DD + d];
    h[(size_t)i * DD + d] = acc;
}

// ---------------------------------------------------------------- counting sort by dst
__global__ __launch_bounds__(256) void hist_kernel(
    const int* __restrict__ dstI, int* __restrict__ hist)
{
    int e = blockIdx.x * 256 + threadIdx.x;
    if (e >= NE) return;
    atomicAdd(&hist[dstI[e]], 1);
}

__global__ __launch_bounds__(256) void scan1_kernel(
    int* __restrict__ hist, int* __restrict__ bsum)
{
    __shared__ int s[256];
    int tid = threadIdx.x;
    int i = blockIdx.x * 256 + tid;
    int v = hist[i];                       // NHB = grid*256 exactly
    s[tid] = v; __syncthreads();
    for (int off = 1; off < 256; off <<= 1) {
        int tmp = (tid >= off) ? s[tid - off] : 0;
        __syncthreads();
        s[tid] += tmp;
        __syncthreads();
    }
    hist[i] = s[tid] - v;                  // exclusive within block
    if (tid == 255) bsum[blockIdx.x] = s[255];
}

__global__ __launch_bounds__(256) void scan2_kernel(
    const int* __restrict__ bsum, int* __restrict__ bsumx)
{
    __shared__ int s[256];
    int tid = threadIdx.x;
    int v = (tid < 196) ? bsum[tid] : 0;
    s[tid] = v; __syncthreads();
    for (int off = 1; off < 256; off <<= 1) {
        int tmp = (tid >= off) ? s[tid - off] : 0;
        __syncthreads();
        s[tid] += tmp;
        __syncthreads();
    }
    if (tid < 196) bsumx[tid] = s[tid] - v;
}

__global__ __launch_bounds__(256) void scan3_kernel(
    int* __restrict__ hist, const int* __restrict__ bsumx)
{
    int i = blockIdx.x * 256 + threadIdx.x;
    hist[i] += bsumx[blockIdx.x];          // hist now = global excl offset (doubles as cursor)
}

__global__ __launch_bounds__(256) void scatter_kernel(
    const int* __restrict__ dstI, int* __restrict__ cursor, int* __restrict__ perm)
{
    int e = blockIdx.x * 256 + threadIdx.x;
    if (e >= NE) return;
    int pos = atomicAdd(&cursor[dstI[e]], 1);
    perm[pos] = e;
}

__global__ __launch_bounds__(256) void permapply_kernel(
    const int* __restrict__ perm, const int* __restrict__ srcI, const int* __restrict__ dstI,
    const float* __restrict__ ea,
    int* __restrict__ srcP, int* __restrict__ dstP, float* __restrict__ eaP)
{
    int i = blockIdx.x * 256 + threadIdx.x;
    if (i >= NE) return;
    int e = perm[i];
    srcP[i] = srcI[e];
    dstP[i] = dstI[e];
    ((float4*)eaP)[i] = ((const float4*)ea)[e];
}

// d2 in permuted order (sorted path)
__global__ __launch_bounds__(256) void d2p_kernel(
    const float* __restrict__ pos, const int* __restrict__ srcP,
    const int* __restrict__ dstP, float* __restrict__ d2)
{
    int e = blockIdx.x * 256 + threadIdx.x;
    if (e >= NE) return;
    int s = srcP[e], d = dstP[e];
    float dx = pos[d * 3 + 0] - pos[s * 3 + 0];
    float dy = pos[d * 3 + 1] - pos[s * 3 + 1];
    float dz = pos[d * 3 + 2] - pos[s * 3 + 2];
    d2[e] = dx * dx + dy * dy + dz * dz;
}

// d2 in original order (fallback path)
__global__ __launch_bounds__(256) void d2_kernel(
    const float* __restrict__ pos, const int* __restrict__ srcI,
    const int* __restrict__ dstI, float* __restrict__ d2)
{
    int e = blockIdx.x * 256 + threadIdx.x;
    if (e >= NE) return;
    int s = srcI[e], d = dstI[e];
    float dx = pos[d * 3 + 0] - pos[s * 3 + 0];
    float dy = pos[d * 3 + 1] - pos[s * 3 + 1];
    float dz = pos[d * 3 + 2] - pos[s * 3 + 2];
    d2[e] = dx * dx + dy * dy + dz * dz;
}

// ---------------------------------------------------------------- node projections P = h @ W1a / W1b
__global__ __launch_bounds__(256, 4) void proj_kernel(
    const float* __restrict__ h, const float* __restrict__ W1, float* __restrict__ P)
{
    __shared__ __align__(16) float A[32][TT];
    __shared__ __align__(16) float B[32][DD];
    int i0 = blockIdx.x * TT;
    int mat = blockIdx.y;
    const float* W = W1 + (size_t)mat * 128 * DD;
    float* out = P + (size_t)mat * NND * DD;
    int t = threadIdx.x;
    int tx = t & 15, ty = t >> 4;
    int e = t & 63, q = t >> 6;
    int node = i0 + e; if (node >= NND) node = NND - 1;
    const float* hrow = h + (size_t)node * DD;

    float acc[4][8];
#pragma unroll
    for (int i = 0; i < 4; ++i)
#pragma unroll
        for (int j = 0; j < 8; ++j) acc[i][j] = 0.0f;

    for (int c = 0; c < 4; ++c) {
        __syncthreads();
        float4 v0 = *(const float4*)(hrow + c * 32 + q * 8);
        float4 v1 = *(const float4*)(hrow + c * 32 + q * 8 + 4);
#pragma unroll
        for (int j = 0; j < 4; ++j) A[q * 8 + j][e]     = (&v0.x)[j];
#pragma unroll
        for (int j = 0; j < 4; ++j) A[q * 8 + 4 + j][e] = (&v1.x)[j];
        const float4* srcp = (const float4*)(W + (size_t)(c * 32) * DD);
        float4* dstp = (float4*)&B[0][0];
#pragma unroll
        for (int r = 0; r < 4; ++r) dstp[t + r * 256] = srcp[t + r * 256];
        __syncthreads();
#pragma unroll 4
        for (int k = 0; k < 32; ++k) {
            float4 a  = *(const float4*)&A[k][tx * 4];
            float4 b0 = *(const float4*)&B[k][ty * 8];
            float4 b1 = *(const float4*)&B[k][ty * 8 + 4];
            float av[4] = {a.x, a.y, a.z, a.w};
            float bv[8] = {b0.x, b0.y, b0.z, b0.w, b1.x, b1.y, b1.z, b1.w};
#pragma unroll
            for (int i = 0; i < 4; ++i)
#pragma unroll
                for (int j = 0; j < 8; ++j) acc[i][j] += av[i] * bv[j];
        }
    }
#pragma unroll
    for (int i = 0; i < 4; ++i) {
        int r = i0 + tx * 4 + i;
        if (r < NND) {
            float4 o0 = {acc[i][0], acc[i][1], acc[i][2], acc[i][3]};
            float4 o1 = {acc[i][4], acc[i][5], acc[i][6], acc[i][7]};
            *(float4*)(out + (size_t)r * DD + ty * 8)     = o0;
            *(float4*)(out + (size_t)r * DD + ty * 8 + 4) = o1;
        }
    }
}

// ---------------------------------------------------------------- message over SORTED edges + merged atomics
__global__ __launch_bounds__(256, 3) void msgs_kernel(
    const float* __restrict__ P, const int* __restrict__ srcP, const int* __restrict__ dstP,
    const float* __restrict__ eaP, const float* __restrict__ d2,
    const float* __restrict__ W1tail, const float* __restrict__ b1,
    const float* __restrict__ W2, const float* __restrict__ b2,
    float* __restrict__ agg)
{
    __shared__ __align__(16) float T[DD][TT];   // 32 KB
    __shared__ __align__(16) float B[32][DD];   // 16 KB
    __shared__ __align__(16) float Wc[5][DD];   // 2.5 KB
    int t = threadIdx.x;
    int e0 = blockIdx.x * TT;
    int tx = t & 15, ty = t >> 4;

    if (t < 160) ((float4*)&Wc[0][0])[t] = ((const float4*)W1tail)[t];
    __syncthreads();

    float4 b1a = *(const float4*)(b1 + ty * 8);
    float4 b1b = *(const float4*)(b1 + ty * 8 + 4);
    float b1v[8] = {b1a.x, b1a.y, b1a.z, b1a.w, b1b.x, b1b.y, b1b.z, b1b.w};

    const float* Pd = P;
    const float* Ps = P + (size_t)NND * DD;

    // coalesced 16B index loads: 4 consecutive sorted edges per thread
    int4 dv4 = *(const int4*)(dstP + e0 + tx * 4);
    int4 sv4 = *(const int4*)(srcP + e0 + tx * 4);
    int dcache[4] = {dv4.x, dv4.y, dv4.z, dv4.w};
    int scache[4] = {sv4.x, sv4.y, sv4.z, sv4.w};

#pragma unroll
    for (int i = 0; i < 4; ++i) {
        int e  = tx * 4 + i;
        const float* pd = Pd + (size_t)dcache[i] * DD + ty * 8;   // sorted: mostly L1-broadcast
        const float* ps = Ps + (size_t)scache[i] * DD + ty * 8;   // random
        float4 p0 = *(const float4*)pd;
        float4 p1 = *(const float4*)(pd + 4);
        float4 q0 = *(const float4*)ps;
        float4 q1 = *(const float4*)(ps + 4);
        float tv[8] = {p0.x + q0.x, p0.y + q0.y, p0.z + q0.z, p0.w + q0.w,
                       p1.x + q1.x, p1.y + q1.y, p1.z + q1.z, p1.w + q1.w};
#pragma unroll
        for (int j = 0; j < 8; ++j) tv[j] += b1v[j];
        float4 av = ((const float4*)eaP)[e0 + e];
        float ev[5] = {av.x, av.y, av.z, av.w, d2[e0 + e]};
#pragma unroll
        for (int qf = 0; qf < 5; ++qf) {
            float xx = ev[qf];
#pragma unroll
            for (int j = 0; j < 8; ++j) tv[j] += xx * Wc[qf][ty * 8 + j];
        }
#pragma unroll
        for (int j = 0; j < 8; ++j) T[ty * 8 + j][e] = fmaxf(tv[j], 0.0f);
    }

    float4 b2a = *(const float4*)(b2 + ty * 8);
    float4 b2b = *(const float4*)(b2 + ty * 8 + 4);
    float acc[4][8];
#pragma unroll
    for (int i = 0; i < 4; ++i) {
        acc[i][0] = b2a.x; acc[i][1] = b2a.y; acc[i][2] = b2a.z; acc[i][3] = b2a.w;
        acc[i][4] = b2b.x; acc[i][5] = b2b.y; acc[i][6] = b2b.z; acc[i][7] = b2b.w;
    }

    for (int c = 0; c < 4; ++c) {
        __syncthreads();                       // 1st iter covers T writes; later: B reads done
        const float4* srcp = (const float4*)(W2 + (size_t)(c * 32) * DD);
        float4* dstp = (float4*)&B[0][0];
#pragma unroll
        for (int r = 0; r < 4; ++r) dstp[t + r * 256] = srcp[t + r * 256];
        __syncthreads();
#pragma unroll 4
        for (int k = 0; k < 32; ++k) {
            float4 a  = *(const float4*)&T[c * 32 + k][tx * 4];
            float4 b0 = *(const float4*)&B[k][ty * 8];
            float4 b1f = *(const float4*)&B[k][ty * 8 + 4];
            float av[4] = {a.x, a.y, a.z, a.w};
            float bv[8] = {b0.x, b0.y, b0.z, b0.w, b1f.x, b1f.y, b1f.z, b1f.w};
#pragma unroll
            for (int i = 0; i < 4; ++i)
#pragma unroll
                for (int j = 0; j < 8; ++j) acc[i][j] += av[i] * bv[j];
        }
    }

    // merged atomic epilogue: consecutive sorted edges sharing dst -> one atomic set
    float sum[8];
    int cur = dcache[0];
#pragma unroll
    for (int j = 0; j < 8; ++j) sum[j] = acc[0][j];
#pragma unroll
    for (int i = 1; i < 4; ++i) {
        if (dcache[i] == cur) {
#pragma unroll
            for (int j = 0; j < 8; ++j) sum[j] += acc[i][j];
        } else {
            float* ag = agg + (size_t)cur * DD + ty * 8;
#pragma unroll
            for (int j = 0; j < 8; ++j) unsafeAtomicAdd(ag + j, sum[j]);
            cur = dcache[i];
#pragma unroll
            for (int j = 0; j < 8; ++j) sum[j] = acc[i][j];
        }
    }
    {
        float* ag = agg + (size_t)cur * DD + ty * 8;
#pragma unroll
        for (int j = 0; j < 8; ++j) unsafeAtomicAdd(ag + j, sum[j]);
    }
}

// ---------------------------------------------------------------- message (factored, unsorted fallback)
__global__ __launch_bounds__(256, 3) void msgf_kernel(
    const float* __restrict__ P, const int* __restrict__ srcI, const int* __restrict__ dstI,
    const float* __restrict__ ea, const float* __restrict__ d2,
    const float* __restrict__ W1tail, const float* __restrict__ b1,
    const float* __restrict__ W2, const float* __restrict__ b2,
    float* __restrict__ agg)
{
    __shared__ __align__(16) float T[DD][TT];
    __shared__ __align__(16) float B[32][DD];
    __shared__ __align__(16) float Wc[5][DD];
    int t = threadIdx.x;
    int e0 = blockIdx.x * TT;
    int tx = t & 15, ty = t >> 4;

    if (t < 160) ((float4*)&Wc[0][0])[t] = ((const float4*)W1tail)[t];
    __syncthreads();

    float4 b1a = *(const float4*)(b1 + ty * 8);
    float4 b1b = *(const float4*)(b1 + ty * 8 + 4);
    float b1v[8] = {b1a.x, b1a.y, b1a.z, b1a.w, b1b.x, b1b.y, b1b.z, b1b.w};

    const float* Pd = P;
    const float* Ps = P + (size_t)NND * DD;
    int dcache[4];
#pragma unroll
    for (int i = 0; i < 4; ++i) {
        int e  = tx * 4 + i;
        int ds = dstI[e0 + e];
        int sr = srcI[e0 + e];
        dcache[i] = ds;
        const float* pd = Pd + (size_t)ds * DD + ty * 8;
        const float* ps = Ps + (size_t)sr * DD + ty * 8;
        float4 p0 = *(const float4*)pd;
        float4 p1 = *(const float4*)(pd + 4);
        float4 q0 = *(const float4*)ps;
        float4 q1 = *(const float4*)(ps + 4);
        float tv[8] = {p0.x + q0.x, p0.y + q0.y, p0.z + q0.z, p0.w + q0.w,
                       p1.x + q1.x, p1.y + q1.y, p1.z + q1.z, p1.w + q1.w};
#pragma unroll
        for (int j = 0; j < 8; ++j) tv[j] += b1v[j];
        float4 av = ((const float4*)ea)[e0 + e];
        float ev[5] = {av.x, av.y, av.z, av.w, d2[e0 + e]};
#pragma unroll
        for (int qf = 0; qf < 5; ++qf) {
            float xx = ev[qf];
#pragma unroll
            for (int j = 0; j < 8; ++j) tv[j] += xx * Wc[qf][ty * 8 + j];
        }
#pragma unroll
        for (int j = 0; j < 8; ++j) T[ty * 8 + j][e] = fmaxf(tv[j], 0.0f);
    }

    float4 b2a = *(const float4*)(b2 + ty * 8);
    float4 b2b = *(const float4*)(b2 + ty * 8 + 4);
    float acc[4][8];
#pragma unroll
    for (int i = 0; i < 4; ++i) {
        acc[i][0] = b2a.x; acc[i][1] = b2a.y; acc[i][2] = b2a.z; acc[i][3] = b2a.w;
        acc[i][4] = b2b.x; acc[i][5] = b2b.y; acc[i][6] = b2b.z; acc[i][7] = b2b.w;
    }

    for (int c = 0; c < 4; ++c) {
        __syncthreads();
        const float4* srcp = (const float4*)(W2 + (size_t)(c * 32) * DD);
        float4* dstp = (float4*)&B[0][0];
#pragma unroll
        for (int r = 0; r < 4; ++r) dstp[t + r * 256] = srcp[t + r * 256];
        __syncthreads();
#pragma unroll 4
        for (int k = 0; k < 32; ++k) {
            float4 a  = *(const float4*)&T[c * 32 + k][tx * 4];
            float4 b0 = *(const float4*)&B[k][ty * 8];
            float4 b1f = *(const float4*)&B[k][ty * 8 + 4];
            float av[4] = {a.x, a.y, a.z, a.w};
            float bv[8] = {b0.x, b0.y, b0.z, b0.w, b1f.x, b1f.y, b1f.z, b1f.w};
#pragma unroll
            for (int i = 0; i < 4; ++i)
#pragma unroll
                for (int j = 0; j < 8; ++j) acc[i][j] += av[i] * bv[j];
        }
    }

#pragma unroll
    for (int i = 0; i < 4; ++i) {
        float* ag = agg + (size_t)dcache[i] * DD + ty * 8;
#pragma unroll
        for (int j = 0; j < 8; ++j) unsafeAtomicAdd(ag + j, acc[i][j]);
    }
}

// ---------------------------------------------------------------- node update: GEMM(K=384) + residual + LN
__global__ __launch_bounds__(256, 2) void upd_kernel(
    float* __restrict__ h, const float* __restrict__ agg,
    const float* __restrict__ W1, const float* __restrict__ b1,
    const float* __restrict__ W2, const float* __restrict__ b2,
    const float* __restrict__ lng, const float* __restrict__ lnb)
{
    __shared__ __align__(16) float A[32][TT];
    __shared__ __align__(16) float T[DD][TT];
    __shared__ __align__(16) float B[32][DD];
    int t = threadIdx.x;
    int i0 = blockIdx.x * TT;
    int tx = t & 15, ty = t >> 4;
    int e = t & 63, q = t >> 6;
    int node = i0 + e; int nclamp = (node < NND) ? node : (NND - 1);

    float4 b1a = *(const float4*)(b1 + ty * 8);
    float4 b1b = *(const float4*)(b1 + ty * 8 + 4);
    float acc[4][8];
#pragma unroll
    for (int i = 0; i < 4; ++i) {
        acc[i][0] = b1a.x; acc[i][1] = b1a.y; acc[i][2] = b1a.z; acc[i][3] = b1a.w;
        acc[i][4] = b1b.x; acc[i][5] = b1b.y; acc[i][6] = b1b.z; acc[i][7] = b1b.w;
    }

    for (int c = 0; c < 8; ++c) {
        __syncthreads();
        const float* row = ((c < 4) ? (h + (size_t)nclamp * DD + c * 32)
                                    : (agg + (size_t)nclamp * DD + (c - 4) * 32));
        float4 v0 = *(const float4*)(row + q * 8);
        float4 v1 = *(const float4*)(row + q * 8 + 4);
#pragma unroll
        for (int j = 0; j < 4; ++j) A[q * 8 + j][e]     = (&v0.x)[j];
#pragma unroll
        for (int j = 0; j < 4; ++j) A[q * 8 + 4 + j][e] = (&v1.x)[j];
        const float4* srcp = (const float4*)(W1 + (size_t)(c * 32) * DD);
        float4* dstp = (float4*)&B[0][0];
#pragma unroll
        for (int r = 0; r < 4; ++r) dstp[t + r * 256] = srcp[t + r * 256];
        __syncthreads();
#pragma unroll 4
        for (int k = 0; k < 32; ++k) {
            float4 a  = *(const float4*)&A[k][tx * 4];
            float4 b0 = *(const float4*)&B[k][ty * 8];
            float4 b1f = *(const float4*)&B[k][ty * 8 + 4];
            float av[4] = {a.x, a.y, a.z, a.w};
            float bv[8] = {b0.x, b0.y, b0.z, b0.w, b1f.x, b1f.y, b1f.z, b1f.w};
#pragma unroll
            for (int i = 0; i < 4; ++i)
#pragma unroll
                for (int j = 0; j < 8; ++j) acc[i][j] += av[i] * bv[j];
        }
    }

#pragma unroll
    for (int i = 0; i < 4; ++i)
#pragma unroll
        for (int j = 0; j < 8; ++j) T[ty * 8 + j][tx * 4 + i] = fmaxf(acc[i][j], 0.0f);

    float4 b2a = *(const float4*)(b2 + ty * 8);
    float4 b2b = *(const float4*)(b2 + ty * 8 + 4);
#pragma unroll
    for (int i = 0; i < 4; ++i) {
        acc[i][0] = b2a.x; acc[i][1] = b2a.y; acc[i][2] = b2a.z; acc[i][3] = b2a.w;
        acc[i][4] = b2b.x; acc[i][5] = b2b.y; acc[i][6] = b2b.z; acc[i][7] = b2b.w;
    }
    for (int c = 0; c < 4; ++c) {
        __syncthreads();
        const float4* srcp = (const float4*)(W2 + (size_t)(c * 32) * DD);
        float4* dstp = (float4*)&B[0][0];
#pragma unroll
        for (int r = 0; r < 4; ++r) dstp[t + r * 256] = srcp[t + r * 256];
        __syncthreads();
#pragma unroll 4
        for (int k = 0; k < 32; ++k) {
            float4 a  = *(const float4*)&T[c * 32 + k][tx * 4];
            float4 b0 = *(const float4*)&B[k][ty * 8];
            float4 b1f = *(const float4*)&B[k][ty * 8 + 4];
            float av[4] = {a.x, a.y, a.z, a.w};
            float bv[8] = {b0.x, b0.y, b0.z, b0.w, b1f.x, b1f.y, b1f.z, b1f.w};
#pragma unroll
            for (int i = 0; i < 4; ++i)
#pragma unroll
                for (int j = 0; j < 8; ++j) acc[i][j] += av[i] * bv[j];
        }
    }

    __syncthreads();
#pragma unroll
    for (int i = 0; i < 4; ++i)
#pragma unroll
        for (int j = 0; j < 8; ++j) T[ty * 8 + j][tx * 4 + i] = acc[i][j];
    __syncthreads();

    if (t < TT) {
        int nd = i0 + t;
        if (nd < NND) {
            float* hrow = h + (size_t)nd * DD;
            float sum = 0.0f;
            for (int o = 0; o < DD; ++o) sum += T[o][t] + hrow[o];
            float mean = sum * (1.0f / DD);
            float var = 0.0f;
            for (int o = 0; o < DD; ++o) {
                float xv = T[o][t] + hrow[o] - mean;
                var += xv * xv;
            }
            var *= (1.0f / DD);
            float inv = 1.0f / sqrtf(var + 1e-5f);
            for (int o = 0; o < DD; ++o) {
                float xv = T[o][t] + hrow[o];
                hrow[o] = (xv - mean) * inv * lng[o] + lnb[o];
            }
        }
    }
}

// ---------------------------------------------------------------- pooling
__global__ __launch_bounds__(256) void cnt_kernel(
    const int* __restrict__ batch, float* __restrict__ cnt)
{
    int i = blockIdx.x * 256 + threadIdx.x;
    if (i >= NND) return;
    unsafeAtomicAdd(&cnt[batch[i]], 1.0f);
}

__global__ __launch_bounds__(256) void pool_kernel(
    const float* __restrict__ h, const int* __restrict__ batch, float* __restrict__ hs)
{
    int t = blockIdx.x * 256 + threadIdx.x;
    int i = t >> 7, d = t & 127;
    if (i >= NND) return;
    unsafeAtomicAdd(&hs[batch[i] * DD + d], h[(size_t)i * DD + d]);
}

// ---------------------------------------------------------------- decoder
__device__ __forceinline__ float softplus_stable(float y) {
    return fmaxf(y, 0.0f) + log1pf(expf(-fabsf(y)));
}

__global__ __launch_bounds__(256) void dec_kernel(
    const float* __restrict__ hs, const float* __restrict__ cnt,
    const float* __restrict__ W1, const float* __restrict__ b1,
    const float* __restrict__ lng, const float* __restrict__ lnb,
    const float* __restrict__ W2, const float* __restrict__ b2,
    const float* __restrict__ W3, const float* __restrict__ b3,
    float* __restrict__ out)
{
    int g  = blockIdx.x >> 1;
    int hd = blockIdx.x & 1;
    int t  = threadIdx.x;
    __shared__ float hg[DD];
    __shared__ float sA[256];
    __shared__ float red[256];

    if (t < DD) {
        float c = fmaxf(cnt[g], 1.0f);
        hg[t] = hs[g * DD + t] / c;
    }
    __syncthreads();

    const float* w1 = W1 + hd * DD * 256;
    float acc = b1[hd * 256 + t];
#pragma unroll 8
    for (int k = 0; k < DD; ++k) acc += hg[k] * w1[k * 256 + t];

    red[t] = acc; __syncthreads();
    for (int s = 128; s > 0; s >>= 1) { if (t < s) red[t] += red[t + s]; __syncthreads(); }
    float mean = red[0] * (1.0f / 256.0f);
    __syncthreads();
    float dv = acc - mean;
    red[t] = dv * dv; __syncthreads();
    for (int s = 128; s > 0; s >>= 1) { if (t < s) red[t] += red[t + s]; __syncthreads(); }
    float var = red[0] * (1.0f / 256.0f);
    float inv = 1.0f / sqrtf(var + 1e-5f);
    float z1 = dv * inv * lng[hd * 256 + t] + lnb[hd * 256 + t];
    z1 = softplus_stable(2.0f * z1) * 0.5f;
    __syncthreads();
    sA[t] = z1; __syncthreads();

    const float* w2 = W2 + hd * 256 * 256;
    float acc2 = b2[hd * 256 + t];
#pragma unroll 8
    for (int k = 0; k < 256; ++k) acc2 += sA[k] * w2[k * 256 + t];
    float z2 = softplus_stable(2.0f * acc2) * 0.5f;
    __syncthreads();
    sA[t] = z2; __syncthreads();

    const float* w3 = W3 + hd * 256 * 300;
    for (int s = t; s < 300; s += 256) {
        float acc3 = b3[hd * 300 + s];
#pragma unroll 8
        for (int k = 0; k < 256; ++k) acc3 += sA[k] * w3[k * 300 + s];
        out[g * 600 + hd * 300 + s] = softplus_stable(acc3);
    }
}

// ---------------------------------------------------------------- launch
extern "C" void kernel_launch(void* const* d_in, const int* in_sizes, int n_in,
                              void* d_out, int out_size, void* d_ws, size_t ws_size,
                              hipStream_t stream)
{
    const float* x     = (const float*)d_in[0];
    const float* pos   = (const float*)d_in[1];
    const float* eattr = (const float*)d_in[2];
    const int*   eidx  = (const int*)d_in[3];
    const int*   batch = (const int*)d_in[4];
    const float* W_in  = (const float*)d_in[5];
    const float* b_in  = (const float*)d_in[6];
    const float* msgW1 = (const float*)d_in[7];
    const float* msgb1 = (const float*)d_in[8];
    const float* msgW2 = (const float*)d_in[9];
    const float* msgb2 = (const float*)d_in[10];
    const float* updW1 = (const float*)d_in[11];
    const float* updb1 = (const float*)d_in[12];
    const float* updW2 = (const float*)d_in[13];
    const float* updb2 = (const float*)d_in[14];
    const float* lng   = (const float*)d_in[15];
    const float* lnb   = (const float*)d_in[16];
    const float* dW1   = (const float*)d_in[17];
    const float* db1   = (const float*)d_in[18];
    const float* dlng  = (const float*)d_in[19];
    const float* dlnb  = (const float*)d_in[20];
    const float* dW2   = (const float*)d_in[21];
    const float* db2   = (const float*)d_in[22];
    const float* dW3   = (const float*)d_in[23];
    const float* db3   = (const float*)d_in[24];

    float* ws  = (float*)d_ws;
    float* h    = ws;                   // N*128
    float* agg  = ws + 6400000;         // N*128
    float* d2   = ws + 12800000;        // E
    float* hsg  = ws + 13600000;        // G*128
    float* cnt  = ws + 13664000;        // G
    float* P    = ws + 13700000;        // 2*N*128
    int*   perm = (int*)(ws + 26500000);    // E
    int*   srcP = (int*)(ws + 27300000);    // E
    int*   dstP = (int*)(ws + 28100000);    // E
    float* eaP  = ws + 28900000;            // E*4
    int*   hist = (int*)(ws + 32100000);    // NHB (doubles as cursor/offset)
    int*   bsum = (int*)(ws + 32150176);    // 256
    int*   bsumx= (int*)(ws + 32150432);    // 256

    const size_t need_sorted   = (size_t)32150688 * 4;
    const size_t need_factored = (size_t)(13700000 + 2 * NND * DD) * 4;
    const bool sorted   = (ws_size >= need_sorted);
    const bool factored = (ws_size >= need_factored);

    const int* srcI = eidx;
    const int* dstI = eidx + NE;

    inproj_kernel<<<25000, 256, 0, stream>>>(x, W_in, b_in, h);

    if (sorted) {
        hipMemsetAsync(hist, 0, (size_t)(NHB + 512) * 4, stream);   // hist+bsum+bsumx
        hist_kernel<<<3125, 256, 0, stream>>>(dstI, hist);
        scan1_kernel<<<196, 256, 0, stream>>>(hist, bsum);
        scan2_kernel<<<1, 256, 0, stream>>>(bsum, bsumx);
        scan3_kernel<<<196, 256, 0, stream>>>(hist, bsumx);
        scatter_kernel<<<3125, 256, 0, stream>>>(dstI, hist, perm);
        permapply_kernel<<<3125, 256, 0, stream>>>(perm, srcI, dstI, eattr, srcP, dstP, eaP);
        d2p_kernel<<<3125, 256, 0, stream>>>(pos, srcP, dstP, d2);
    } else {
        d2_kernel<<<3125, 256, 0, stream>>>(pos, srcI, dstI, d2);
    }

    const int nblk_nodes = (NND + TT - 1) / TT;   // 782
    const int nblk_edges = NE / TT;               // 12500

    for (int l = 0; l < 4; ++l) {
        const float* W1l = msgW1 + (size_t)l * 261 * 128;
        hipMemsetAsync(agg, 0, 6400000 * sizeof(float), stream);
        if (sorted) {
            proj_kernel<<<dim3(nblk_nodes, 2), 256, 0, stream>>>(h, W1l, P);
            msgs_kernel<<<nblk_edges, 256, 0, stream>>>(P, srcP, dstP, eaP, d2,
                W1l + 256 * 128, msgb1 + l * 128,
                msgW2 + (size_t)l * 128 * 128, msgb2 + l * 128, agg);
        } else if (factored) {
            proj_kernel<<<dim3(nblk_nodes, 2), 256, 0, stream>>>(h, W1l, P);
            msgf_kernel<<<nblk_edges, 256, 0, stream>>>(P, srcI, dstI, eattr, d2,
                W1l + 256 * 128, msgb1 + l * 128,
                msgW2 + (size_t)l * 128 * 128, msgb2 + l * 128, agg);
        }
        upd_kernel<<<nblk_nodes, 256, 0, stream>>>(h, agg,
            updW1 + (size_t)l * 256 * 128, updb1 + l * 128,
            updW2 + (size_t)l * 128 * 128, updb2 + l * 128,
            lng + l * 128, lnb + l * 128);
    }

    hipMemsetAsync(hsg, 0, 64500 * sizeof(float), stream);
    cnt_kernel<<<196, 256, 0, stream>>>(batch, cnt);
    pool_kernel<<<25000, 256, 0, stream>>>(h, batch, hsg);
    dec_kernel<<<1000, 256, 0, stream>>>(hsg, cnt, dW1, db1, dlng, dlnb,
                                         dW2, db2, dW3, db3, (float*)d_out);
}

// Round 7
// 2233.582 us; speedup vs baseline: 11.4306x; 3.2221x over previous
//
#include <hip/hip_runtime.h>
#include <cstdint>
#include <cstddef>

#define NND 50000
#define NE  800000
#define DD  128
#define NG  500
#define TT  64      // tile rows (edges/nodes) per block
#define NHB 50176   // hist size, padded to 196*256 exactly

typedef __attribute__((ext_vector_type(8))) short short8v;
typedef __attribute__((ext_vector_type(4))) float float4v;

// fp32 -> bf16 (RNE), no NaN handling needed for this workload
__device__ __forceinline__ short f2bf(float f) {
    unsigned u = __builtin_bit_cast(unsigned, f);
    unsigned r = (u + 0x7FFFu + ((u >> 16) & 1u)) >> 16;
    return (short)r;
}

// ---------------------------------------------------------------- input proj
__global__ __launch_bounds__(256) void inproj_kernel(
    const float* __restrict__ x, const float* __restrict__ W,
    const float* __restrict__ b, float* __restrict__ h)
{
    int t = blockIdx.x * 256 + threadIdx.x;
    int i = t >> 7, d = t & 127;
    if (i >= NND) return;
    const float* xr = x + (size_t)i * 11;
    float acc = b[d];
#pragma unroll
    for (int k = 0; k < 11; ++k) acc += xr[k] * W[k * DD + d];
    h[(size_t)i * DD + d] = acc;
}

// ---------------------------------------------------------------- counting sort by dst
__global__ __launch_bounds__(256) void hist_kernel(
    const int* __restrict__ dstI, int* __restrict__ hist)
{
    int e = blockIdx.x * 256 + threadIdx.x;
    if (e >= NE) return;
    atomicAdd(&hist[dstI[e]], 1);
}

__global__ __launch_bounds__(256) void scan1_kernel(
    int* __restrict__ hist, int* __restrict__ bsum)
{
    __shared__ int s[256];
    int tid = threadIdx.x;
    int i = blockIdx.x * 256 + tid;
    int v = hist[i];
    s[tid] = v; __syncthreads();
    for (int off = 1; off < 256; off <<= 1) {
        int tmp = (tid >= off) ? s[tid - off] : 0;
        __syncthreads();
        s[tid] += tmp;
        __syncthreads();
    }
    hist[i] = s[tid] - v;
    if (tid == 255) bsum[blockIdx.x] = s[255];
}

__global__ __launch_bounds__(256) void scan2_kernel(
    const int* __restrict__ bsum, int* __restrict__ bsumx)
{
    __shared__ int s[256];
    int tid = threadIdx.x;
    int v = (tid < 196) ? bsum[tid] : 0;
    s[tid] = v; __syncthreads();
    for (int off = 1; off < 256; off <<= 1) {
        int tmp = (tid >= off) ? s[tid - off] : 0;
        __syncthreads();
        s[tid] += tmp;
        __syncthreads();
    }
    if (tid < 196) bsumx[tid] = s[tid] - v;
}

__global__ __launch_bounds__(256) void scan3_kernel(
    int* __restrict__ hist, const int* __restrict__ bsumx)
{
    int i = blockIdx.x * 256 + threadIdx.x;
    hist[i] += bsumx[blockIdx.x];
}

__global__ __launch_bounds__(256) void scatter_kernel(
    const int* __restrict__ dstI, int* __restrict__ cursor, int* __restrict__ perm)
{
    int e = blockIdx.x * 256 + threadIdx.x;
    if (e >= NE) return;
    int pos = atomicAdd(&cursor[dstI[e]], 1);
    perm[pos] = e;
}

__global__ __launch_bounds__(256) void permapply_kernel(
    const int* __restrict__ perm, const int* __restrict__ srcI, const int* __restrict__ dstI,
    const float* __restrict__ ea,
    int* __restrict__ srcP, int* __restrict__ dstP, float* __restrict__ eaP)
{
    int i = blockIdx.x * 256 + threadIdx.x;
    if (i >= NE) return;
    int e = perm[i];
    srcP[i] = srcI[e];
    dstP[i] = dstI[e];
    ((float4*)eaP)[i] = ((const float4*)ea)[e];
}

__global__ __launch_bounds__(256) void d2p_kernel(
    const float* __restrict__ pos, const int* __restrict__ srcP,
    const int* __restrict__ dstP, float* __restrict__ d2)
{
    int e = blockIdx.x * 256 + threadIdx.x;
    if (e >= NE) return;
    int s = srcP[e], d = dstP[e];
    float dx = pos[d * 3 + 0] - pos[s * 3 + 0];
    float dy = pos[d * 3 + 1] - pos[s * 3 + 1];
    float dz = pos[d * 3 + 2] - pos[s * 3 + 2];
    d2[e] = dx * dx + dy * dy + dz * dz;
}

__global__ __launch_bounds__(256) void d2_kernel(
    const float* __restrict__ pos, const int* __restrict__ srcI,
    const int* __restrict__ dstI, float* __restrict__ d2)
{
    int e = blockIdx.x * 256 + threadIdx.x;
    if (e >= NE) return;
    int s = srcI[e], d = dstI[e];
    float dx = pos[d * 3 + 0] - pos[s * 3 + 0];
    float dy = pos[d * 3 + 1] - pos[s * 3 + 1];
    float dz = pos[d * 3 + 2] - pos[s * 3 + 2];
    d2[e] = dx * dx + dy * dy + dz * dz;
}

// ---------------------------------------------------------------- W2 -> bf16, transposed [n][k], PRE-SWIZZLED for LDS
// global W2t[p]: n = p>>7, qphys = (p&127)>>3, j = p&7, kg = qphys ^ (n&7), k = kg*8+j
// so a linear LDS copy + XOR-swizzled read yields W2[k][n] fragments.
__global__ __launch_bounds__(256) void w2prep_kernel(
    const float* __restrict__ W2, short* __restrict__ W2t)
{
    int p = blockIdx.x * 256 + threadIdx.x;   // grid 64 -> 16384
    int n = p >> 7;
    int q = (p & 127) >> 3;
    int j = p & 7;
    int kg = q ^ (n & 7);
    W2t[p] = f2bf(W2[(kg * 8 + j) * DD + n]);
}

// ---------------------------------------------------------------- node projections P = h @ W1a / W1b
__global__ __launch_bounds__(256, 4) void proj_kernel(
    const float* __restrict__ h, const float* __restrict__ W1, float* __restrict__ P)
{
    __shared__ __align__(16) float A[32][TT];
    __shared__ __align__(16) float B[32][DD];
    int i0 = blockIdx.x * TT;
    int mat = blockIdx.y;
    const float* W = W1 + (size_t)mat * 128 * DD;
    float* out = P + (size_t)mat * NND * DD;
    int t = threadIdx.x;
    int tx = t & 15, ty = t >> 4;
    int e = t & 63, q = t >> 6;
    int node = i0 + e; if (node >= NND) node = NND - 1;
    const float* hrow = h + (size_t)node * DD;

    float acc[4][8];
#pragma unroll
    for (int i = 0; i < 4; ++i)
#pragma unroll
        for (int j = 0; j < 8; ++j) acc[i][j] = 0.0f;

    for (int c = 0; c < 4; ++c) {
        __syncthreads();
        float4 v0 = *(const float4*)(hrow + c * 32 + q * 8);
        float4 v1 = *(const float4*)(hrow + c * 32 + q * 8 + 4);
#pragma unroll
        for (int j = 0; j < 4; ++j) A[q * 8 + j][e]     = (&v0.x)[j];
#pragma unroll
        for (int j = 0; j < 4; ++j) A[q * 8 + 4 + j][e] = (&v1.x)[j];
        const float4* srcp = (const float4*)(W + (size_t)(c * 32) * DD);
        float4* dstp = (float4*)&B[0][0];
#pragma unroll
        for (int r = 0; r < 4; ++r) dstp[t + r * 256] = srcp[t + r * 256];
        __syncthreads();
#pragma unroll 4
        for (int k = 0; k < 32; ++k) {
            float4 a  = *(const float4*)&A[k][tx * 4];
            float4 b0 = *(const float4*)&B[k][ty * 8];
            float4 b1 = *(const float4*)&B[k][ty * 8 + 4];
            float av[4] = {a.x, a.y, a.z, a.w};
            float bv[8] = {b0.x, b0.y, b0.z, b0.w, b1.x, b1.y, b1.z, b1.w};
#pragma unroll
            for (int i = 0; i < 4; ++i)
#pragma unroll
                for (int j = 0; j < 8; ++j) acc[i][j] += av[i] * bv[j];
        }
    }
#pragma unroll
    for (int i = 0; i < 4; ++i) {
        int r = i0 + tx * 4 + i;
        if (r < NND) {
            float4 o0 = {acc[i][0], acc[i][1], acc[i][2], acc[i][3]};
            float4 o1 = {acc[i][4], acc[i][5], acc[i][6], acc[i][7]};
            *(float4*)(out + (size_t)r * DD + ty * 8)     = o0;
            *(float4*)(out + (size_t)r * DD + ty * 8 + 4) = o1;
        }
    }
}

// ---------------------------------------------------------------- message, SORTED edges, stage-2 via bf16 MFMA
// stage-1 fp32: T = relu(Pd[dst]+Ps[src]+ea@Wc+b1) -> bf16 LDS (XOR-swizzled)
// stage-2: M = T @ W2 via mfma_f32_16x16x32_bf16, fp32 accum; merged atomics
__global__ __launch_bounds__(256, 3) void msgm_kernel(
    const float* __restrict__ P, const int* __restrict__ srcP, const int* __restrict__ dstP,
    const float* __restrict__ eaP, const float* __restrict__ d2,
    const float* __restrict__ W1tail, const float* __restrict__ b1,
    const short* __restrict__ W2t, const float* __restrict__ b2,
    float* __restrict__ agg)
{
    __shared__ __align__(16) short Tld[64 * 128];     // 16 KB bf16
    __shared__ __align__(16) short W2ld[128 * 128];   // 32 KB bf16 (pre-swizzled)
    int t = threadIdx.x;
    int e0 = blockIdx.x * TT;
    int tx = t & 15, ty = t >> 4;

    // ---- stage W2t: linear coalesced copy (swizzle already in global layout)
    {
        const short8v* g = (const short8v*)W2t;
        short8v* l = (short8v*)W2ld;
#pragma unroll
        for (int p = 0; p < 8; ++p) l[t + p * 256] = g[t + p * 256];
    }

    // ---- Wc (W1 rows 256..260) into regs; wave-uniform per ty -> L1 broadcast
    float wc[5][8];
#pragma unroll
    for (int qf = 0; qf < 5; ++qf) {
        float4 a0 = *(const float4*)(W1tail + qf * DD + ty * 8);
        float4 a1 = *(const float4*)(W1tail + qf * DD + ty * 8 + 4);
        wc[qf][0] = a0.x; wc[qf][1] = a0.y; wc[qf][2] = a0.z; wc[qf][3] = a0.w;
        wc[qf][4] = a1.x; wc[qf][5] = a1.y; wc[qf][6] = a1.z; wc[qf][7] = a1.w;
    }

    float4 b1a = *(const float4*)(b1 + ty * 8);
    float4 b1b = *(const float4*)(b1 + ty * 8 + 4);
    float b1v[8] = {b1a.x, b1a.y, b1a.z, b1a.w, b1b.x, b1b.y, b1b.z, b1b.w};

    const float* Pd = P;
    const float* Ps = P + (size_t)NND * DD;

    int4 dv4 = *(const int4*)(dstP + e0 + tx * 4);
    int4 sv4 = *(const int4*)(srcP + e0 + tx * 4);
    int dcache[4] = {dv4.x, dv4.y, dv4.z, dv4.w};
    int scache[4] = {sv4.x, sv4.y, sv4.z, sv4.w};

#pragma unroll
    for (int i = 0; i < 4; ++i) {
        int e = tx * 4 + i;
        const float* pd = Pd + (size_t)dcache[i] * DD + ty * 8;
        const float* ps = Ps + (size_t)scache[i] * DD + ty * 8;
        float4 p0 = *(const float4*)pd;
        float4 p1 = *(const float4*)(pd + 4);
        float4 q0 = *(const float4*)ps;
        float4 q1 = *(const float4*)(ps + 4);
        float tv[8] = {p0.x + q0.x, p0.y + q0.y, p0.z + q0.z, p0.w + q0.w,
                       p1.x + q1.x, p1.y + q1.y, p1.z + q1.z, p1.w + q1.w};
#pragma unroll
        for (int j = 0; j < 8; ++j) tv[j] += b1v[j];
        float4 av = ((const float4*)eaP)[e0 + e];
        float ev[5] = {av.x, av.y, av.z, av.w, d2[e0 + e]};
#pragma unroll
        for (int qf = 0; qf < 5; ++qf) {
            float xx = ev[qf];
#pragma unroll
            for (int j = 0; j < 8; ++j) tv[j] += xx * wc[qf][j];
        }
        short8v pk;
#pragma unroll
        for (int j = 0; j < 8; ++j) pk[j] = f2bf(fmaxf(tv[j], 0.0f));
        int colg = ty ^ (e & 7);                        // XOR swizzle (write side)
        *(short8v*)&Tld[e * 128 + colg * 8] = pk;
    }

    __syncthreads();   // T + W2ld visible

    // ---- MFMA: each wave owns 16 edge-rows x 128 cols
    int lane = t & 63, w = t >> 6;
    int lg = lane >> 4;
    int m  = w * 16 + (lane & 15);
    float4v acc[8];
#pragma unroll
    for (int i = 0; i < 8; ++i) acc[i] = (float4v){0.f, 0.f, 0.f, 0.f};

#pragma unroll
    for (int ks = 0; ks < 4; ++ks) {
        int kg = ks * 4 + lg;
        short8v afrag = *(const short8v*)&Tld[m * 128 + ((kg ^ (m & 7)) << 3)];
#pragma unroll
        for (int nt = 0; nt < 8; ++nt) {
            int n = nt * 16 + (lane & 15);
            short8v bfrag = *(const short8v*)&W2ld[n * 128 + ((kg ^ (n & 7)) << 3)];
            acc[nt] = __builtin_amdgcn_mfma_f32_16x16x32_bf16(afrag, bfrag, acc[nt], 0, 0, 0);
        }
    }

    // ---- epilogue: D row = w*16 + lg*4 + r, col = nt*16 + (lane&15); merged atomics
    int base_e = e0 + w * 16 + (lg << 2);
    int4 dq = *(const int4*)(dstP + base_e);
    int drow[4] = {dq.x, dq.y, dq.z, dq.w};
    float b2c[8];
#pragma unroll
    for (int nt = 0; nt < 8; ++nt) b2c[nt] = b2[nt * 16 + (lane & 15)];

    float sum[8];
    int cur = drow[0];
#pragma unroll
    for (int nt = 0; nt < 8; ++nt) sum[nt] = acc[nt][0] + b2c[nt];
#pragma unroll
    for (int r = 1; r < 4; ++r) {
        if (drow[r] == cur) {
#pragma unroll
            for (int nt = 0; nt < 8; ++nt) sum[nt] += acc[nt][r] + b2c[nt];
        } else {
            float* ag = agg + (size_t)cur * DD + (lane & 15);
#pragma unroll
            for (int nt = 0; nt < 8; ++nt) unsafeAtomicAdd(ag + nt * 16, sum[nt]);
            cur = drow[r];
#pragma unroll
            for (int nt = 0; nt < 8; ++nt) sum[nt] = acc[nt][r] + b2c[nt];
        }
    }
    float* ag = agg + (size_t)cur * DD + (lane & 15);
#pragma unroll
    for (int nt = 0; nt < 8; ++nt) unsafeAtomicAdd(ag + nt * 16, sum[nt]);
}

// ---------------------------------------------------------------- message (factored fp32, unsorted fallback)
__global__ __launch_bounds__(256, 3) void msgf_kernel(
    const float* __restrict__ P, const int* __restrict__ srcI, const int* __restrict__ dstI,
    const float* __restrict__ ea, const float* __restrict__ d2,
    const float* __restrict__ W1tail, const float* __restrict__ b1,
    const float* __restrict__ W2, const float* __restrict__ b2,
    float* __restrict__ agg)
{
    __shared__ __align__(16) float T[DD][TT];
    __shared__ __align__(16) float B[32][DD];
    __shared__ __align__(16) float Wc[5][DD];
    int t = threadIdx.x;
    int e0 = blockIdx.x * TT;
    int tx = t & 15, ty = t >> 4;

    if (t < 160) ((float4*)&Wc[0][0])[t] = ((const float4*)W1tail)[t];
    __syncthreads();

    float4 b1a = *(const float4*)(b1 + ty * 8);
    float4 b1b = *(const float4*)(b1 + ty * 8 + 4);
    float b1v[8] = {b1a.x, b1a.y, b1a.z, b1a.w, b1b.x, b1b.y, b1b.z, b1b.w};

    const float* Pd = P;
    const float* Ps = P + (size_t)NND * DD;
    int dcache[4];
#pragma unroll
    for (int i = 0; i < 4; ++i) {
        int e  = tx * 4 + i;
        int ds = dstI[e0 + e];
        int sr = srcI[e0 + e];
        dcache[i] = ds;
        const float* pd = Pd + (size_t)ds * DD + ty * 8;
        const float* ps = Ps + (size_t)sr * DD + ty * 8;
        float4 p0 = *(const float4*)pd;
        float4 p1 = *(const float4*)(pd + 4);
        float4 q0 = *(const float4*)ps;
        float4 q1 = *(const float4*)(ps + 4);
        float tv[8] = {p0.x + q0.x, p0.y + q0.y, p0.z + q0.z, p0.w + q0.w,
                       p1.x + q1.x, p1.y + q1.y, p1.z + q1.z, p1.w + q1.w};
#pragma unroll
        for (int j = 0; j < 8; ++j) tv[j] += b1v[j];
        float4 av = ((const float4*)ea)[e0 + e];
        float ev[5] = {av.x, av.y, av.z, av.w, d2[e0 + e]};
#pragma unroll
        for (int qf = 0; qf < 5; ++qf) {
            float xx = ev[qf];
#pragma unroll
            for (int j = 0; j < 8; ++j) tv[j] += xx * Wc[qf][ty * 8 + j];
        }
#pragma unroll
        for (int j = 0; j < 8; ++j) T[ty * 8 + j][e] = fmaxf(tv[j], 0.0f);
    }

    float4 b2a = *(const float4*)(b2 + ty * 8);
    float4 b2b = *(const float4*)(b2 + ty * 8 + 4);
    float acc[4][8];
#pragma unroll
    for (int i = 0; i < 4; ++i) {
        acc[i][0] = b2a.x; acc[i][1] = b2a.y; acc[i][2] = b2a.z; acc[i][3] = b2a.w;
        acc[i][4] = b2b.x; acc[i][5] = b2b.y; acc[i][6] = b2b.z; acc[i][7] = b2b.w;
    }

    for (int c = 0; c < 4; ++c) {
        __syncthreads();
        const float4* srcp = (const float4*)(W2 + (size_t)(c * 32) * DD);
        float4* dstp = (float4*)&B[0][0];
#pragma unroll
        for (int r = 0; r < 4; ++r) dstp[t + r * 256] = srcp[t + r * 256];
        __syncthreads();
#pragma unroll 4
        for (int k = 0; k < 32; ++k) {
            float4 a  = *(const float4*)&T[c * 32 + k][tx * 4];
            float4 b0 = *(const float4*)&B[k][ty * 8];
            float4 b1f = *(const float4*)&B[k][ty * 8 + 4];
            float av[4] = {a.x, a.y, a.z, a.w};
            float bv[8] = {b0.x, b0.y, b0.z, b0.w, b1f.x, b1f.y, b1f.z, b1f.w};
#pragma unroll
            for (int i = 0; i < 4; ++i)
#pragma unroll
                for (int j = 0; j < 8; ++j) acc[i][j] += av[i] * bv[j];
        }
    }

#pragma unroll
    for (int i = 0; i < 4; ++i) {
        float* ag = agg + (size_t)dcache[i] * DD + ty * 8;
#pragma unroll
        for (int j = 0; j < 8; ++j) unsafeAtomicAdd(ag + j, acc[i][j]);
    }
}

// ---------------------------------------------------------------- node update: GEMM(K=384) + residual + LN
__global__ __launch_bounds__(256, 2) void upd_kernel(
    float* __restrict__ h, const float* __restrict__ agg,
    const float* __restrict__ W1, const float* __restrict__ b1,
    const float* __restrict__ W2, const float* __restrict__ b2,
    const float* __restrict__ lng, const float* __restrict__ lnb)
{
    __shared__ __align__(16) float A[32][TT];
    __shared__ __align__(16) float T[DD][TT];
    __shared__ __align__(16) float B[32][DD];
    int t = threadIdx.x;
    int i0 = blockIdx.x * TT;
    int tx = t & 15, ty = t >> 4;
    int e = t & 63, q = t >> 6;
    int node = i0 + e; int nclamp = (node < NND) ? node : (NND - 1);

    float4 b1a = *(const float4*)(b1 + ty * 8);
    float4 b1b = *(const float4*)(b1 + ty * 8 + 4);
    float acc[4][8];
#pragma unroll
    for (int i = 0; i < 4; ++i) {
        acc[i][0] = b1a.x; acc[i][1] = b1a.y; acc[i][2] = b1a.z; acc[i][3] = b1a.w;
        acc[i][4] = b1b.x; acc[i][5] = b1b.y; acc[i][6] = b1b.z; acc[i][7] = b1b.w;
    }

    for (int c = 0; c < 8; ++c) {
        __syncthreads();
        const float* row = ((c < 4) ? (h + (size_t)nclamp * DD + c * 32)
                                    : (agg + (size_t)nclamp * DD + (c - 4) * 32));
        float4 v0 = *(const float4*)(row + q * 8);
        float4 v1 = *(const float4*)(row + q * 8 + 4);
#pragma unroll
        for (int j = 0; j < 4; ++j) A[q * 8 + j][e]     = (&v0.x)[j];
#pragma unroll
        for (int j = 0; j < 4; ++j) A[q * 8 + 4 + j][e] = (&v1.x)[j];
        const float4* srcp = (const float4*)(W1 + (size_t)(c * 32) * DD);
        float4* dstp = (float4*)&B[0][0];
#pragma unroll
        for (int r = 0; r < 4; ++r) dstp[t + r * 256] = srcp[t + r * 256];
        __syncthreads();
#pragma unroll 4
        for (int k = 0; k < 32; ++k) {
            float4 a  = *(const float4*)&A[k][tx * 4];
            float4 b0 = *(const float4*)&B[k][ty * 8];
            float4 b1f = *(const float4*)&B[k][ty * 8 + 4];
            float av[4] = {a.x, a.y, a.z, a.w};
            float bv[8] = {b0.x, b0.y, b0.z, b0.w, b1f.x, b1f.y, b1f.z, b1f.w};
#pragma unroll
            for (int i = 0; i < 4; ++i)
#pragma unroll
                for (int j = 0; j < 8; ++j) acc[i][j] += av[i] * bv[j];
        }
    }

#pragma unroll
    for (int i = 0; i < 4; ++i)
#pragma unroll
        for (int j = 0; j < 8; ++j) T[ty * 8 + j][tx * 4 + i] = fmaxf(acc[i][j], 0.0f);

    float4 b2a = *(const float4*)(b2 + ty * 8);
    float4 b2b = *(const float4*)(b2 + ty * 8 + 4);
#pragma unroll
    for (int i = 0; i < 4; ++i) {
        acc[i][0] = b2a.x; acc[i][1] = b2a.y; acc[i][2] = b2a.z; acc[i][3] = b2a.w;
        acc[i][4] = b2b.x; acc[i][5] = b2b.y; acc[i][6] = b2b.z; acc[i][7] = b2b.w;
    }
    for (int c = 0; c < 4; ++c) {
        __syncthreads();
        const float4* srcp = (const float4*)(W2 + (size_t)(c * 32) * DD);
        float4* dstp = (float4*)&B[0][0];
#pragma unroll
        for (int r = 0; r < 4; ++r) dstp[t + r * 256] = srcp[t + r * 256];
        __syncthreads();
#pragma unroll 4
        for (int k = 0; k < 32; ++k) {
            float4 a  = *(const float4*)&T[c * 32 + k][tx * 4];
            float4 b0 = *(const float4*)&B[k][ty * 8];
            float4 b1f = *(const float4*)&B[k][ty * 8 + 4];
            float av[4] = {a.x, a.y, a.z, a.w};
            float bv[8] = {b0.x, b0.y, b0.z, b0.w, b1f.x, b1f.y, b1f.z, b1f.w};
#pragma unroll
            for (int i = 0; i < 4; ++i)
#pragma unroll
                for (int j = 0; j < 8; ++j) acc[i][j] += av[i] * bv[j];
        }
    }

    __syncthreads();
#pragma unroll
    for (int i = 0; i < 4; ++i)
#pragma unroll
        for (int j = 0; j < 8; ++j) T[ty * 8 + j][tx * 4 + i] = acc[i][j];
    __syncthreads();

    if (t < TT) {
        int nd = i0 + t;
        if (nd < NND) {
            float* hrow = h + (size_t)nd * DD;
            float sum = 0.0f;
            for (int o = 0; o < DD; ++o) sum += T[o][t] + hrow[o];
            float mean = sum * (1.0f / DD);
            float var = 0.0f;
            for (int o = 0; o < DD; ++o) {
                float xv = T[o][t] + hrow[o] - mean;
                var += xv * xv;
            }
            var *= (1.0f / DD);
            float inv = 1.0f / sqrtf(var + 1e-5f);
            for (int o = 0; o < DD; ++o) {
                float xv = T[o][t] + hrow[o];
                hrow[o] = (xv - mean) * inv * lng[o] + lnb[o];
            }
        }
    }
}

// ---------------------------------------------------------------- pooling
__global__ __launch_bounds__(256) void cnt_kernel(
    const int* __restrict__ batch, float* __restrict__ cnt)
{
    int i = blockIdx.x * 256 + threadIdx.x;
    if (i >= NND) return;
    unsafeAtomicAdd(&cnt[batch[i]], 1.0f);
}

__global__ __launch_bounds__(256) void pool_kernel(
    const float* __restrict__ h, const int* __restrict__ batch, float* __restrict__ hs)
{
    int t = blockIdx.x * 256 + threadIdx.x;
    int i = t >> 7, d = t & 127;
    if (i >= NND) return;
    unsafeAtomicAdd(&hs[batch[i] * DD + d], h[(size_t)i * DD + d]);
}

// ---------------------------------------------------------------- decoder
__device__ __forceinline__ float softplus_stable(float y) {
    return fmaxf(y, 0.0f) + log1pf(expf(-fabsf(y)));
}

__global__ __launch_bounds__(256) void dec_kernel(
    const float* __restrict__ hs, const float* __restrict__ cnt,
    const float* __restrict__ W1, const float* __restrict__ b1,
    const float* __restrict__ lng, const float* __restrict__ lnb,
    const float* __restrict__ W2, const float* __restrict__ b2,
    const float* __restrict__ W3, const float* __restrict__ b3,
    float* __restrict__ out)
{
    int g  = blockIdx.x >> 1;
    int hd = blockIdx.x & 1;
    int t  = threadIdx.x;
    __shared__ float hg[DD];
    __shared__ float sA[256];
    __shared__ float red[256];

    if (t < DD) {
        float c = fmaxf(cnt[g], 1.0f);
        hg[t] = hs[g * DD + t] / c;
    }
    __syncthreads();

    const float* w1 = W1 + hd * DD * 256;
    float acc = b1[hd * 256 + t];
#pragma unroll 8
    for (int k = 0; k < DD; ++k) acc += hg[k] * w1[k * 256 + t];

    red[t] = acc; __syncthreads();
    for (int s = 128; s > 0; s >>= 1) { if (t < s) red[t] += red[t + s]; __syncthreads(); }
    float mean = red[0] * (1.0f / 256.0f);
    __syncthreads();
    float dv = acc - mean;
    red[t] = dv * dv; __syncthreads();
    for (int s = 128; s > 0; s >>= 1) { if (t < s) red[t] += red[t + s]; __syncthreads(); }
    float var = red[0] * (1.0f / 256.0f);
    float inv = 1.0f / sqrtf(var + 1e-5f);
    float z1 = dv * inv * lng[hd * 256 + t] + lnb[hd * 256 + t];
    z1 = softplus_stable(2.0f * z1) * 0.5f;
    __syncthreads();
    sA[t] = z1; __syncthreads();

    const float* w2 = W2 + hd * 256 * 256;
    float acc2 = b2[hd * 256 + t];
#pragma unroll 8
    for (int k = 0; k < 256; ++k) acc2 += sA[k] * w2[k * 256 + t];
    float z2 = softplus_stable(2.0f * acc2) * 0.5f;
    __syncthreads();
    sA[t] = z2; __syncthreads();

    const float* w3 = W3 + hd * 256 * 300;
    for (int s = t; s < 300; s += 256) {
        float acc3 = b3[hd * 300 + s];
#pragma unroll 8
        for (int k = 0; k < 256; ++k) acc3 += sA[k] * w3[k * 300 + s];
        out[g * 600 + hd * 300 + s] = softplus_stable(acc3);
    }
}

// ---------------------------------------------------------------- launch
extern "C" void kernel_launch(void* const* d_in, const int* in_sizes, int n_in,
                              void* d_out, int out_size, void* d_ws, size_t ws_size,
                              hipStream_t stream)
{
    const float* x     = (const float*)d_in[0];
    const float* pos   = (const float*)d_in[1];
    const float* eattr = (const float*)d_in[2];
    const int*   eidx  = (const int*)d_in[3];
    const int*   batch = (const int*)d_in[4];
    const float* W_in  = (const float*)d_in[5];
    const float* b_in  = (const float*)d_in[6];
    const float* msgW1 = (const float*)d_in[7];
    const float* msgb1 = (const float*)d_in[8];
    const float* msgW2 = (const float*)d_in[9];
    const float* msgb2 = (const float*)d_in[10];
    const float* updW1 = (const float*)d_in[11];
    const float* updb1 = (const float*)d_in[12];
    const float* updW2 = (const float*)d_in[13];
    const float* updb2 = (const float*)d_in[14];
    const float* lng   = (const float*)d_in[15];
    const float* lnb   = (const float*)d_in[16];
    const float* dW1   = (const float*)d_in[17];
    const float* db1   = (const float*)d_in[18];
    const float* dlng  = (const float*)d_in[19];
    const float* dlnb  = (const float*)d_in[20];
    const float* dW2   = (const float*)d_in[21];
    const float* db2   = (const float*)d_in[22];
    const float* dW3   = (const float*)d_in[23];
    const float* db3   = (const float*)d_in[24];

    float* ws  = (float*)d_ws;
    float* h    = ws;                   // N*128
    float* agg  = ws + 6400000;         // N*128
    float* d2   = ws + 12800000;        // E
    float* hsg  = ws + 13600000;        // G*128
    float* cnt  = ws + 13664000;        // G (500)
    short* W2t  = (short*)(ws + 13666000);  // 16384 bf16 (8192 floats, fits gap before P)
    float* P    = ws + 13700000;        // 2*N*128
    int*   perm = (int*)(ws + 26500000);    // E
    int*   srcP = (int*)(ws + 27300000);    // E
    int*   dstP = (int*)(ws + 28100000);    // E
    float* eaP  = ws + 28900000;            // E*4
    int*   hist = (int*)(ws + 32100000);    // NHB
    int*   bsum = (int*)(ws + 32150176);    // 256
    int*   bsumx= (int*)(ws + 32150432);    // 256

    const size_t need_sorted   = (size_t)32150688 * 4;
    const size_t need_factored = (size_t)(13700000 + 2 * NND * DD) * 4;
    const bool sorted   = (ws_size >= need_sorted);
    const bool factored = (ws_size >= need_factored);

    const int* srcI = eidx;
    const int* dstI = eidx + NE;

    inproj_kernel<<<25000, 256, 0, stream>>>(x, W_in, b_in, h);

    if (sorted) {
        hipMemsetAsync(hist, 0, (size_t)(NHB + 512) * 4, stream);
        hist_kernel<<<3125, 256, 0, stream>>>(dstI, hist);
        scan1_kernel<<<196, 256, 0, stream>>>(hist, bsum);
        scan2_kernel<<<1, 256, 0, stream>>>(bsum, bsumx);
        scan3_kernel<<<196, 256, 0, stream>>>(hist, bsumx);
        scatter_kernel<<<3125, 256, 0, stream>>>(dstI, hist, perm);
        permapply_kernel<<<3125, 256, 0, stream>>>(perm, srcI, dstI, eattr, srcP, dstP, eaP);
        d2p_kernel<<<3125, 256, 0, stream>>>(pos, srcP, dstP, d2);
    } else {
        d2_kernel<<<3125, 256, 0, stream>>>(pos, srcI, dstI, d2);
    }

    const int nblk_nodes = (NND + TT - 1) / TT;   // 782
    const int nblk_edges = NE / TT;               // 12500

    for (int l = 0; l < 4; ++l) {
        const float* W1l = msgW1 + (size_t)l * 261 * 128;
        hipMemsetAsync(agg, 0, 6400000 * sizeof(float), stream);
        if (sorted) {
            w2prep_kernel<<<64, 256, 0, stream>>>(msgW2 + (size_t)l * 128 * 128, W2t);
            proj_kernel<<<dim3(nblk_nodes, 2), 256, 0, stream>>>(h, W1l, P);
            msgm_kernel<<<nblk_edges, 256, 0, stream>>>(P, srcP, dstP, eaP, d2,
                W1l + 256 * 128, msgb1 + l * 128, W2t, msgb2 + l * 128, agg);
        } else if (factored) {
            proj_kernel<<<dim3(nblk_nodes, 2), 256, 0, stream>>>(h, W1l, P);
            msgf_kernel<<<nblk_edges, 256, 0, stream>>>(P, srcI, dstI, eattr, d2,
                W1l + 256 * 128, msgb1 + l * 128,
                msgW2 + (size_t)l * 128 * 128, msgb2 + l * 128, agg);
        }
        upd_kernel<<<nblk_nodes, 256, 0, stream>>>(h, agg,
            updW1 + (size_t)l * 256 * 128, updb1 + l * 128,
            updW2 + (size_t)l * 128 * 128, updb2 + l * 128,
            lng + l * 128, lnb + l * 128);
    }

    hipMemsetAsync(hsg, 0, 64500 * sizeof(float), stream);
    cnt_kernel<<<196, 256, 0, stream>>>(batch, cnt);
    pool_kernel<<<25000, 256, 0, stream>>>(h, batch, hsg);
    dec_kernel<<<1000, 256, 0, stream>>>(hsg, cnt, dW1, db1, dlng, dlnb,
                                         dW2, db2, dW3, db3, (float*)d_out);
}

// Round 8
// 1848.769 us; speedup vs baseline: 13.8099x; 1.2081x over previous
//
#include <hip/hip_runtime.h>
#include <cstdint>
#include <cstddef>

#define NND 50000
#define NE  800000
#define DD  128
#define NG  500
#define TT  64      // tile rows (edges/nodes) per block
#define NHB 50176   // hist size, padded to 196*256 exactly

typedef __attribute__((ext_vector_type(8))) short short8v;
typedef __attribute__((ext_vector_type(4))) float float4v;

// A-side LDS swizzle: logical k-group g of row -> physical group.
// Bijective per row; spreads 8 consecutive-lane writes over all 8 bank groups.
#define SWZA(row, g) ((g) ^ ((row) & 7) ^ (((row) >> 3) & 7))

// fp32 -> bf16 (RNE)
__device__ __forceinline__ short f2bf(float f) {
    unsigned u = __builtin_bit_cast(unsigned, f);
    unsigned r = (u + 0x7FFFu + ((u >> 16) & 1u)) >> 16;
    return (short)r;
}

// ---------------------------------------------------------------- input proj
__global__ __launch_bounds__(256) void inproj_kernel(
    const float* __restrict__ x, const float* __restrict__ W,
    const float* __restrict__ b, float* __restrict__ h)
{
    int t = blockIdx.x * 256 + threadIdx.x;
    int i = t >> 7, d = t & 127;
    if (i >= NND) return;
    const float* xr = x + (size_t)i * 11;
    float acc = b[d];
#pragma unroll
    for (int k = 0; k < 11; ++k) acc += xr[k] * W[k * DD + d];
    h[(size_t)i * DD + d] = acc;
}

// ---------------------------------------------------------------- counting sort by dst
__global__ __launch_bounds__(256) void hist_kernel(
    const int* __restrict__ dstI, int* __restrict__ hist)
{
    int e = blockIdx.x * 256 + threadIdx.x;
    if (e >= NE) return;
    atomicAdd(&hist[dstI[e]], 1);
}

__global__ __launch_bounds__(256) void scan1_kernel(
    int* __restrict__ hist, int* __restrict__ bsum)
{
    __shared__ int s[256];
    int tid = threadIdx.x;
    int i = blockIdx.x * 256 + tid;
    int v = hist[i];
    s[tid] = v; __syncthreads();
    for (int off = 1; off < 256; off <<= 1) {
        int tmp = (tid >= off) ? s[tid - off] : 0;
        __syncthreads();
        s[tid] += tmp;
        __syncthreads();
    }
    hist[i] = s[tid] - v;
    if (tid == 255) bsum[blockIdx.x] = s[255];
}

__global__ __launch_bounds__(256) void scan2_kernel(
    const int* __restrict__ bsum, int* __restrict__ bsumx)
{
    __shared__ int s[256];
    int tid = threadIdx.x;
    int v = (tid < 196) ? bsum[tid] : 0;
    s[tid] = v; __syncthreads();
    for (int off = 1; off < 256; off <<= 1) {
        int tmp = (tid >= off) ? s[tid - off] : 0;
        __syncthreads();
        s[tid] += tmp;
        __syncthreads();
    }
    if (tid < 196) bsumx[tid] = s[tid] - v;
}

__global__ __launch_bounds__(256) void scan3_kernel(
    int* __restrict__ hist, const int* __restrict__ bsumx)
{
    int i = blockIdx.x * 256 + threadIdx.x;
    hist[i] += bsumx[blockIdx.x];
}

__global__ __launch_bounds__(256) void scatter_kernel(
    const int* __restrict__ dstI, int* __restrict__ cursor, int* __restrict__ perm)
{
    int e = blockIdx.x * 256 + threadIdx.x;
    if (e >= NE) return;
    int pos = atomicAdd(&cursor[dstI[e]], 1);
    perm[pos] = e;
}

__global__ __launch_bounds__(256) void permapply_kernel(
    const int* __restrict__ perm, const int* __restrict__ srcI, const int* __restrict__ dstI,
    const float* __restrict__ ea,
    int* __restrict__ srcP, int* __restrict__ dstP, float* __restrict__ eaP)
{
    int i = blockIdx.x * 256 + threadIdx.x;
    if (i >= NE) return;
    int e = perm[i];
    srcP[i] = srcI[e];
    dstP[i] = dstI[e];
    ((float4*)eaP)[i] = ((const float4*)ea)[e];
}

__global__ __launch_bounds__(256) void d2p_kernel(
    const float* __restrict__ pos, const int* __restrict__ srcP,
    const int* __restrict__ dstP, float* __restrict__ d2)
{
    int e = blockIdx.x * 256 + threadIdx.x;
    if (e >= NE) return;
    int s = srcP[e], d = dstP[e];
    float dx = pos[d * 3 + 0] - pos[s * 3 + 0];
    float dy = pos[d * 3 + 1] - pos[s * 3 + 1];
    float dz = pos[d * 3 + 2] - pos[s * 3 + 2];
    d2[e] = dx * dx + dy * dy + dz * dz;
}

__global__ __launch_bounds__(256) void d2_kernel(
    const float* __restrict__ pos, const int* __restrict__ srcI,
    const int* __restrict__ dstI, float* __restrict__ d2)
{
    int e = blockIdx.x * 256 + threadIdx.x;
    if (e >= NE) return;
    int s = srcI[e], d = dstI[e];
    float dx = pos[d * 3 + 0] - pos[s * 3 + 0];
    float dy = pos[d * 3 + 1] - pos[s * 3 + 1];
    float dz = pos[d * 3 + 2] - pos[s * 3 + 2];
    d2[e] = dx * dx + dy * dy + dz * dz;
}

// ---------------------------------------------------------------- per-layer weight prep: 6 chunks of [128][128]
// bf16, stored [n][qphys][j] with qphys = kg ^ (n&7) so linear LDS copy + B-read
// `W[n*128 + ((kg^(n&7))<<3)]` yields W[k][n] fragments.
// chunks: 0 msgW2 | 1 updW1 rows 0..127 | 2 updW1 rows 128..255 | 3 updW2
//         4 msgW1 rows 0..127 (proj A) | 5 msgW1 rows 128..255 (proj B)
__global__ __launch_bounds__(256) void wprep_kernel(
    const float* __restrict__ msgW2, const float* __restrict__ updW1,
    const float* __restrict__ updW2, const float* __restrict__ msgW1,
    short* __restrict__ out)
{
    int p = blockIdx.x * 256 + threadIdx.x;   // grid 384 -> 98304
    int chunk = p >> 14;
    int idx = p & 16383;
    int n = idx >> 7;
    int q = (idx & 127) >> 3;
    int j = idx & 7;
    int k = (q ^ (n & 7)) * 8 + j;
    const float* src;
    if      (chunk == 0) src = msgW2;
    else if (chunk == 1) src = updW1;
    else if (chunk == 2) src = updW1 + 128 * DD;
    else if (chunk == 3) src = updW2;
    else if (chunk == 4) src = msgW1;
    else                 src = msgW1 + 128 * DD;
    out[p] = f2bf(src[k * DD + n]);
}

// ---------------------------------------------------------------- MFMA node projections: P0 = h@W1a, P1 = h@W1b
__global__ __launch_bounds__(256, 3) void projm_kernel(
    const float* __restrict__ h, const short* __restrict__ Wa, const short* __restrict__ Wb,
    float* __restrict__ P)
{
    __shared__ __align__(16) short A[64 * 128];    // 16 KB
    __shared__ __align__(16) short W[128 * 128];   // 32 KB
    int t = threadIdx.x;
    int i0 = blockIdx.x * TT;

    // stage A <- h tile (bf16, SWZA): 4 threads/row, coalesced 512B/row
    {
        int e = t >> 2;
        int node = i0 + e; if (node >= NND) node = NND - 1;
        const float* hr = h + (size_t)node * DD;
#pragma unroll
        for (int j = 0; j < 4; ++j) {
            int g = (t & 3) * 4 + j;
            float4 v0 = *(const float4*)(hr + g * 8);
            float4 v1 = *(const float4*)(hr + g * 8 + 4);
            short8v pk;
            pk[0]=f2bf(v0.x); pk[1]=f2bf(v0.y); pk[2]=f2bf(v0.z); pk[3]=f2bf(v0.w);
            pk[4]=f2bf(v1.x); pk[5]=f2bf(v1.y); pk[6]=f2bf(v1.z); pk[7]=f2bf(v1.w);
            *(short8v*)&A[e * 128 + SWZA(e, g) * 8] = pk;
        }
    }
    {
        const short8v* g = (const short8v*)Wa;
        short8v* l = (short8v*)W;
#pragma unroll
        for (int p = 0; p < 8; ++p) l[t + p * 256] = g[t + p * 256];
    }
    __syncthreads();

    int lane = t & 63, w = t >> 6;
    int c = lane & 15, lg = lane >> 4;
    int m = w * 16 + c;

    for (int mat = 0; mat < 2; ++mat) {
        float4v acc[8];
#pragma unroll
        for (int i = 0; i < 8; ++i) acc[i] = (float4v){0.f, 0.f, 0.f, 0.f};
#pragma unroll
        for (int ks = 0; ks < 4; ++ks) {
            int kg = ks * 4 + lg;
            short8v afrag = *(const short8v*)&A[m * 128 + SWZA(m, kg) * 8];
#pragma unroll
            for (int nt = 0; nt < 8; ++nt) {
                int n = nt * 16 + c;
                short8v bfrag = *(const short8v*)&W[n * 128 + ((kg ^ (n & 7)) << 3)];
                acc[nt] = __builtin_amdgcn_mfma_f32_16x16x32_bf16(afrag, bfrag, acc[nt], 0, 0, 0);
            }
        }
        float* out = P + (size_t)mat * NND * DD;
#pragma unroll
        for (int reg = 0; reg < 4; ++reg) {
            int node = i0 + w * 16 + lg * 4 + reg;
            if (node < NND) {
#pragma unroll
                for (int nt = 0; nt < 8; ++nt)
                    out[(size_t)node * DD + nt * 16 + c] = acc[nt][reg];
            }
        }
        if (mat == 0) {
            __syncthreads();   // all W reads done
            const short8v* g = (const short8v*)Wb;
            short8v* l = (short8v*)W;
#pragma unroll
            for (int p = 0; p < 8; ++p) l[t + p * 256] = g[t + p * 256];
            __syncthreads();
        }
    }
}

// ---------------------------------------------------------------- message, SORTED edges, stage-2 via bf16 MFMA
__global__ __launch_bounds__(256, 3) void msgm_kernel(
    const float* __restrict__ P, const int* __restrict__ srcP, const int* __restrict__ dstP,
    const float* __restrict__ eaP, const float* __restrict__ d2,
    const float* __restrict__ W1tail, const float* __restrict__ b1,
    const short* __restrict__ W2t, const float* __restrict__ b2,
    float* __restrict__ agg)
{
    __shared__ __align__(16) short Tld[64 * 128];     // 16 KB bf16
    __shared__ __align__(16) short W2ld[128 * 128];   // 32 KB bf16 (pre-swizzled)
    int t = threadIdx.x;
    int e0 = blockIdx.x * TT;
    int tx = t & 15, ty = t >> 4;

    {
        const short8v* g = (const short8v*)W2t;
        short8v* l = (short8v*)W2ld;
#pragma unroll
        for (int p = 0; p < 8; ++p) l[t + p * 256] = g[t + p * 256];
    }

    float wc[5][8];
#pragma unroll
    for (int qf = 0; qf < 5; ++qf) {
        float4 a0 = *(const float4*)(W1tail + qf * DD + ty * 8);
        float4 a1 = *(const float4*)(W1tail + qf * DD + ty * 8 + 4);
        wc[qf][0] = a0.x; wc[qf][1] = a0.y; wc[qf][2] = a0.z; wc[qf][3] = a0.w;
        wc[qf][4] = a1.x; wc[qf][5] = a1.y; wc[qf][6] = a1.z; wc[qf][7] = a1.w;
    }

    float4 b1a = *(const float4*)(b1 + ty * 8);
    float4 b1b = *(const float4*)(b1 + ty * 8 + 4);
    float b1v[8] = {b1a.x, b1a.y, b1a.z, b1a.w, b1b.x, b1b.y, b1b.z, b1b.w};

    const float* Pd = P;
    const float* Ps = P + (size_t)NND * DD;

    int4 dv4 = *(const int4*)(dstP + e0 + tx * 4);
    int4 sv4 = *(const int4*)(srcP + e0 + tx * 4);
    int dcache[4] = {dv4.x, dv4.y, dv4.z, dv4.w};
    int scache[4] = {sv4.x, sv4.y, sv4.z, sv4.w};

#pragma unroll
    for (int i = 0; i < 4; ++i) {
        int e = tx * 4 + i;
        const float* pd = Pd + (size_t)dcache[i] * DD + ty * 8;
        const float* ps = Ps + (size_t)scache[i] * DD + ty * 8;
        float4 p0 = *(const float4*)pd;
        float4 p1 = *(const float4*)(pd + 4);
        float4 q0 = *(const float4*)ps;
        float4 q1 = *(const float4*)(ps + 4);
        float tv[8] = {p0.x + q0.x, p0.y + q0.y, p0.z + q0.z, p0.w + q0.w,
                       p1.x + q1.x, p1.y + q1.y, p1.z + q1.z, p1.w + q1.w};
#pragma unroll
        for (int j = 0; j < 8; ++j) tv[j] += b1v[j];
        float4 av = ((const float4*)eaP)[e0 + e];
        float ev[5] = {av.x, av.y, av.z, av.w, d2[e0 + e]};
#pragma unroll
        for (int qf = 0; qf < 5; ++qf) {
            float xx = ev[qf];
#pragma unroll
            for (int j = 0; j < 8; ++j) tv[j] += xx * wc[qf][j];
        }
        short8v pk;
#pragma unroll
        for (int j = 0; j < 8; ++j) pk[j] = f2bf(fmaxf(tv[j], 0.0f));
        *(short8v*)&Tld[e * 128 + SWZA(e, ty) * 8] = pk;
    }

    __syncthreads();

    int lane = t & 63, w = t >> 6;
    int lg = lane >> 4;
    int m  = w * 16 + (lane & 15);
    float4v acc[8];
#pragma unroll
    for (int i = 0; i < 8; ++i) acc[i] = (float4v){0.f, 0.f, 0.f, 0.f};

#pragma unroll
    for (int ks = 0; ks < 4; ++ks) {
        int kg = ks * 4 + lg;
        short8v afrag = *(const short8v*)&Tld[m * 128 + SWZA(m, kg) * 8];
#pragma unroll
        for (int nt = 0; nt < 8; ++nt) {
            int n = nt * 16 + (lane & 15);
            short8v bfrag = *(const short8v*)&W2ld[n * 128 + ((kg ^ (n & 7)) << 3)];
            acc[nt] = __builtin_amdgcn_mfma_f32_16x16x32_bf16(afrag, bfrag, acc[nt], 0, 0, 0);
        }
    }

    int base_e = e0 + w * 16 + (lg << 2);
    int4 dq = *(const int4*)(dstP + base_e);
    int drow[4] = {dq.x, dq.y, dq.z, dq.w};
    float b2c[8];
#pragma unroll
    for (int nt = 0; nt < 8; ++nt) b2c[nt] = b2[nt * 16 + (lane & 15)];

    float sum[8];
    int cur = drow[0];
#pragma unroll
    for (int nt = 0; nt < 8; ++nt) sum[nt] = acc[nt][0] + b2c[nt];
#pragma unroll
    for (int r = 1; r < 4; ++r) {
        if (drow[r] == cur) {
#pragma unroll
            for (int nt = 0; nt < 8; ++nt) sum[nt] += acc[nt][r] + b2c[nt];
        } else {
            float* ag = agg + (size_t)cur * DD + (lane & 15);
#pragma unroll
            for (int nt = 0; nt < 8; ++nt) unsafeAtomicAdd(ag + nt * 16, sum[nt]);
            cur = drow[r];
#pragma unroll
            for (int nt = 0; nt < 8; ++nt) sum[nt] = acc[nt][r] + b2c[nt];
        }
    }
    float* ag = agg + (size_t)cur * DD + (lane & 15);
#pragma unroll
    for (int nt = 0; nt < 8; ++nt) unsafeAtomicAdd(ag + nt * 16, sum[nt]);
}

// ---------------------------------------------------------------- MFMA node update + residual + LN
__global__ __launch_bounds__(256, 3) void updm_kernel(
    float* __restrict__ h, const float* __restrict__ agg,
    const short* __restrict__ W1a, const short* __restrict__ W1b, const short* __restrict__ W2s,
    const float* __restrict__ b1, const float* __restrict__ b2,
    const float* __restrict__ lng, const float* __restrict__ lnb)
{
    __shared__ __align__(16) short A[64 * 128];    // 16 KB (h tile / agg tile / T, reused)
    __shared__ __align__(16) short W[128 * 128];   // 32 KB
    int t = threadIdx.x;
    int i0 = blockIdx.x * TT;
    int lane = t & 63, w = t >> 6;
    int c = lane & 15, lg = lane >> 4;
    int m = w * 16 + c;

    // ---- stage A <- h tile, W <- W1a
    {
        int e = t >> 2;
        int node = i0 + e; if (node >= NND) node = NND - 1;
        const float* hr = h + (size_t)node * DD;
#pragma unroll
        for (int j = 0; j < 4; ++j) {
            int g = (t & 3) * 4 + j;
            float4 v0 = *(const float4*)(hr + g * 8);
            float4 v1 = *(const float4*)(hr + g * 8 + 4);
            short8v pk;
            pk[0]=f2bf(v0.x); pk[1]=f2bf(v0.y); pk[2]=f2bf(v0.z); pk[3]=f2bf(v0.w);
            pk[4]=f2bf(v1.x); pk[5]=f2bf(v1.y); pk[6]=f2bf(v1.z); pk[7]=f2bf(v1.w);
            *(short8v*)&A[e * 128 + SWZA(e, g) * 8] = pk;
        }
        const short8v* gg = (const short8v*)W1a;
        short8v* l = (short8v*)W;
#pragma unroll
        for (int p = 0; p < 8; ++p) l[t + p * 256] = gg[t + p * 256];
    }
    __syncthreads();

    float4v acc[8];
#pragma unroll
    for (int i = 0; i < 8; ++i) acc[i] = (float4v){0.f, 0.f, 0.f, 0.f};

#pragma unroll
    for (int ks = 0; ks < 4; ++ks) {
        int kg = ks * 4 + lg;
        short8v afrag = *(const short8v*)&A[m * 128 + SWZA(m, kg) * 8];
#pragma unroll
        for (int nt = 0; nt < 8; ++nt) {
            int n = nt * 16 + c;
            short8v bfrag = *(const short8v*)&W[n * 128 + ((kg ^ (n & 7)) << 3)];
            acc[nt] = __builtin_amdgcn_mfma_f32_16x16x32_bf16(afrag, bfrag, acc[nt], 0, 0, 0);
        }
    }
    __syncthreads();   // A/W reads done

    // ---- stage A <- agg tile, W <- W1b; accumulate
    {
        int e = t >> 2;
        int node = i0 + e; if (node >= NND) node = NND - 1;
        const float* ar = agg + (size_t)node * DD;
#pragma unroll
        for (int j = 0; j < 4; ++j) {
            int g = (t & 3) * 4 + j;
            float4 v0 = *(const float4*)(ar + g * 8);
            float4 v1 = *(const float4*)(ar + g * 8 + 4);
            short8v pk;
            pk[0]=f2bf(v0.x); pk[1]=f2bf(v0.y); pk[2]=f2bf(v0.z); pk[3]=f2bf(v0.w);
            pk[4]=f2bf(v1.x); pk[5]=f2bf(v1.y); pk[6]=f2bf(v1.z); pk[7]=f2bf(v1.w);
            *(short8v*)&A[e * 128 + SWZA(e, g) * 8] = pk;
        }
        const short8v* gg = (const short8v*)W1b;
        short8v* l = (short8v*)W;
#pragma unroll
        for (int p = 0; p < 8; ++p) l[t + p * 256] = gg[t + p * 256];
    }
    __syncthreads();

#pragma unroll
    for (int ks = 0; ks < 4; ++ks) {
        int kg = ks * 4 + lg;
        short8v afrag = *(const short8v*)&A[m * 128 + SWZA(m, kg) * 8];
#pragma unroll
        for (int nt = 0; nt < 8; ++nt) {
            int n = nt * 16 + c;
            short8v bfrag = *(const short8v*)&W[n * 128 + ((kg ^ (n & 7)) << 3)];
            acc[nt] = __builtin_amdgcn_mfma_f32_16x16x32_bf16(afrag, bfrag, acc[nt], 0, 0, 0);
        }
    }
    __syncthreads();   // A/W reads done

    // ---- bias+ReLU -> T into A (bf16, SWZA); stage W <- W2
    {
        float b1c[8];
#pragma unroll
        for (int nt = 0; nt < 8; ++nt) b1c[nt] = b1[nt * 16 + c];
#pragma unroll
        for (int reg = 0; reg < 4; ++reg) {
            int rowT = w * 16 + lg * 4 + reg;
#pragma unroll
            for (int nt = 0; nt < 8; ++nt) {
                int col = nt * 16 + c;
                int colg = col >> 3;
                float v = fmaxf(acc[nt][reg] + b1c[nt], 0.0f);
                A[rowT * 128 + SWZA(rowT, colg) * 8 + (col & 7)] = f2bf(v);
            }
        }
        const short8v* gg = (const short8v*)W2s;
        short8v* l = (short8v*)W;
#pragma unroll
        for (int p = 0; p < 8; ++p) l[t + p * 256] = gg[t + p * 256];
    }
    __syncthreads();

    // ---- stage-2 MFMA
#pragma unroll
    for (int i = 0; i < 8; ++i) acc[i] = (float4v){0.f, 0.f, 0.f, 0.f};
#pragma unroll
    for (int ks = 0; ks < 4; ++ks) {
        int kg = ks * 4 + lg;
        short8v afrag = *(const short8v*)&A[m * 128 + SWZA(m, kg) * 8];
#pragma unroll
        for (int nt = 0; nt < 8; ++nt) {
            int n = nt * 16 + c;
            short8v bfrag = *(const short8v*)&W[n * 128 + ((kg ^ (n & 7)) << 3)];
            acc[nt] = __builtin_amdgcn_mfma_f32_16x16x32_bf16(afrag, bfrag, acc[nt], 0, 0, 0);
        }
    }

    // ---- epilogue: + b2 + residual, LayerNorm over 128 cols (two-pass, 16-lane shfl reduce)
    float b2c[8], lngc[8], lnbc[8];
#pragma unroll
    for (int nt = 0; nt < 8; ++nt) {
        b2c[nt]  = b2[nt * 16 + c];
        lngc[nt] = lng[nt * 16 + c];
        lnbc[nt] = lnb[nt * 16 + c];
    }
    float xx[8][4];
#pragma unroll
    for (int reg = 0; reg < 4; ++reg) {
        int node = i0 + w * 16 + lg * 4 + reg;
        int nclamp = (node < NND) ? node : (NND - 1);
        const float* hr = h + (size_t)nclamp * DD;
#pragma unroll
        for (int nt = 0; nt < 8; ++nt)
            xx[nt][reg] = acc[nt][reg] + b2c[nt] + hr[nt * 16 + c];
    }
    float s[4] = {0.f, 0.f, 0.f, 0.f};
#pragma unroll
    for (int reg = 0; reg < 4; ++reg)
#pragma unroll
        for (int nt = 0; nt < 8; ++nt) s[reg] += xx[nt][reg];
#pragma unroll
    for (int msk = 1; msk < 16; msk <<= 1)
#pragma unroll
        for (int reg = 0; reg < 4; ++reg) s[reg] += __shfl_xor(s[reg], msk, 64);
    float mean[4];
#pragma unroll
    for (int reg = 0; reg < 4; ++reg) mean[reg] = s[reg] * (1.0f / DD);
    float v[4] = {0.f, 0.f, 0.f, 0.f};
#pragma unroll
    for (int reg = 0; reg < 4; ++reg)
#pragma unroll
        for (int nt = 0; nt < 8; ++nt) {
            float dv = xx[nt][reg] - mean[reg];
            v[reg] += dv * dv;
        }
#pragma unroll
    for (int msk = 1; msk < 16; msk <<= 1)
#pragma unroll
        for (int reg = 0; reg < 4; ++reg) v[reg] += __shfl_xor(v[reg], msk, 64);
#pragma unroll
    for (int reg = 0; reg < 4; ++reg) {
        int node = i0 + w * 16 + lg * 4 + reg;
        if (node < NND) {
            float inv = 1.0f / sqrtf(v[reg] * (1.0f / DD) + 1e-5f);
            float* hw = h + (size_t)node * DD;
#pragma unroll
            for (int nt = 0; nt < 8; ++nt)
                hw[nt * 16 + c] = (xx[nt][reg] - mean[reg]) * inv * lngc[nt] + lnbc[nt];
        }
    }
}

// ---------------------------------------------------------------- fallback: unfactored fp32 message (K=261 GEMM)
__global__ __launch_bounds__(256, 2) void msgu_kernel(
    const float* __restrict__ h, const int* __restrict__ srcI, const int* __restrict__ dstI,
    const float* __restrict__ ea, const float* __restrict__ d2,
    const float* __restrict__ W1, const float* __restrict__ b1,
    const float* __restrict__ W2, const float* __restrict__ b2,
    float* __restrict__ agg)
{
    __shared__ __align__(16) float A[32][TT];
    __shared__ __align__(16) float T[DD][TT];
    __shared__ __align__(16) float B[32][DD];
    int t = threadIdx.x;
    int e0 = blockIdx.x * TT;
    int tx = t & 15, ty = t >> 4;
    int e = t & 63, q = t >> 6;
    int dn = dstI[e0 + e], sn = srcI[e0 + e];

    float4 b1a = *(const float4*)(b1 + ty * 8);
    float4 b1b = *(const float4*)(b1 + ty * 8 + 4);
    float acc[4][8];
#pragma unroll
    for (int i = 0; i < 4; ++i) {
        acc[i][0] = b1a.x; acc[i][1] = b1a.y; acc[i][2] = b1a.z; acc[i][3] = b1a.w;
        acc[i][4] = b1b.x; acc[i][5] = b1b.y; acc[i][6] = b1b.z; acc[i][7] = b1b.w;
    }

    for (int cc = 0; cc < 9; ++cc) {
        int kmax = (cc == 8) ? 5 : 32;
        __syncthreads();
        if (cc < 8) {
            const float* row = h + (size_t)((cc < 4) ? dn : sn) * DD + (cc & 3) * 32;
            float4 v0 = *(const float4*)(row + q * 8);
            float4 v1 = *(const float4*)(row + q * 8 + 4);
#pragma unroll
            for (int j = 0; j < 4; ++j) A[q * 8 + j][e]     = (&v0.x)[j];
#pragma unroll
            for (int j = 0; j < 4; ++j) A[q * 8 + 4 + j][e] = (&v1.x)[j];
        } else if (t < TT) {
            float4 av = ((const float4*)ea)[e0 + t];
            A[0][t] = av.x; A[1][t] = av.y; A[2][t] = av.z; A[3][t] = av.w;
            A[4][t] = d2[e0 + t];
        }
        const float4* srcp = (const float4*)(W1 + (size_t)(cc * 32) * DD);
        float4* dstp = (float4*)&B[0][0];
        if (cc < 8) {
#pragma unroll
            for (int r = 0; r < 4; ++r) dstp[t + r * 256] = srcp[t + r * 256];
        } else if (t < 160) {
            dstp[t] = srcp[t];
        }
        __syncthreads();
        for (int k = 0; k < kmax; ++k) {
            float4 a  = *(const float4*)&A[k][tx * 4];
            float4 b0 = *(const float4*)&B[k][ty * 8];
            float4 b1f = *(const float4*)&B[k][ty * 8 + 4];
            float av[4] = {a.x, a.y, a.z, a.w};
            float bv[8] = {b0.x, b0.y, b0.z, b0.w, b1f.x, b1f.y, b1f.z, b1f.w};
#pragma unroll
            for (int i = 0; i < 4; ++i)
#pragma unroll
                for (int j = 0; j < 8; ++j) acc[i][j] += av[i] * bv[j];
        }
    }

#pragma unroll
    for (int i = 0; i < 4; ++i)
#pragma unroll
        for (int j = 0; j < 8; ++j) T[ty * 8 + j][tx * 4 + i] = fmaxf(acc[i][j], 0.0f);

    float4 b2a = *(const float4*)(b2 + ty * 8);
    float4 b2b = *(const float4*)(b2 + ty * 8 + 4);
#pragma unroll
    for (int i = 0; i < 4; ++i) {
        acc[i][0] = b2a.x; acc[i][1] = b2a.y; acc[i][2] = b2a.z; acc[i][3] = b2a.w;
        acc[i][4] = b2b.x; acc[i][5] = b2b.y; acc[i][6] = b2b.z; acc[i][7] = b2b.w;
    }
    for (int cc = 0; cc < 4; ++cc) {
        __syncthreads();
        const float4* srcp = (const float4*)(W2 + (size_t)(cc * 32) * DD);
        float4* dstp = (float4*)&B[0][0];
#pragma unroll
        for (int r = 0; r < 4; ++r) dstp[t + r * 256] = srcp[t + r * 256];
        __syncthreads();
#pragma unroll 4
        for (int k = 0; k < 32; ++k) {
            float4 a  = *(const float4*)&T[cc * 32 + k][tx * 4];
            float4 b0 = *(const float4*)&B[k][ty * 8];
            float4 b1f = *(const float4*)&B[k][ty * 8 + 4];
            float av[4] = {a.x, a.y, a.z, a.w};
            float bv[8] = {b0.x, b0.y, b0.z, b0.w, b1f.x, b1f.y, b1f.z, b1f.w};
#pragma unroll
            for (int i = 0; i < 4; ++i)
#pragma unroll
                for (int j = 0; j < 8; ++j) acc[i][j] += av[i] * bv[j];
        }
    }
#pragma unroll
    for (int i = 0; i < 4; ++i) {
        int d = dstI[e0 + tx * 4 + i];
        float* ag = agg + (size_t)d * DD + ty * 8;
#pragma unroll
        for (int j = 0; j < 8; ++j) unsafeAtomicAdd(ag + j, acc[i][j]);
    }
}

// ---------------------------------------------------------------- fallback: fp32 node update
__global__ __launch_bounds__(256, 2) void updf_kernel(
    float* __restrict__ h, const float* __restrict__ agg,
    const float* __restrict__ W1, const float* __restrict__ b1,
    const float* __restrict__ W2, const float* __restrict__ b2,
    const float* __restrict__ lng, const float* __restrict__ lnb)
{
    __shared__ __align__(16) float A[32][TT];
    __shared__ __align__(16) float T[DD][TT];
    __shared__ __align__(16) float B[32][DD];
    int t = threadIdx.x;
    int i0 = blockIdx.x * TT;
    int tx = t & 15, ty = t >> 4;
    int e = t & 63, q = t >> 6;
    int node = i0 + e; int nclamp = (node < NND) ? node : (NND - 1);

    float4 b1a = *(const float4*)(b1 + ty * 8);
    float4 b1b = *(const float4*)(b1 + ty * 8 + 4);
    float acc[4][8];
#pragma unroll
    for (int i = 0; i < 4; ++i) {
        acc[i][0] = b1a.x; acc[i][1] = b1a.y; acc[i][2] = b1a.z; acc[i][3] = b1a.w;
        acc[i][4] = b1b.x; acc[i][5] = b1b.y; acc[i][6] = b1b.z; acc[i][7] = b1b.w;
    }

    for (int cc = 0; cc < 8; ++cc) {
        __syncthreads();
        const float* row = ((cc < 4) ? (h + (size_t)nclamp * DD + cc * 32)
                                     : (agg + (size_t)nclamp * DD + (cc - 4) * 32));
        float4 v0 = *(const float4*)(row + q * 8);
        float4 v1 = *(const float4*)(row + q * 8 + 4);
#pragma unroll
        for (int j = 0; j < 4; ++j) A[q * 8 + j][e]     = (&v0.x)[j];
#pragma unroll
        for (int j = 0; j < 4; ++j) A[q * 8 + 4 + j][e] = (&v1.x)[j];
        const float4* srcp = (const float4*)(W1 + (size_t)(cc * 32) * DD);
        float4* dstp = (float4*)&B[0][0];
#pragma unroll
        for (int r = 0; r < 4; ++r) dstp[t + r * 256] = srcp[t + r * 256];
        __syncthreads();
#pragma unroll 4
        for (int k = 0; k < 32; ++k) {
            float4 a  = *(const float4*)&A[k][tx * 4];
            float4 b0 = *(const float4*)&B[k][ty * 8];
            float4 b1f = *(const float4*)&B[k][ty * 8 + 4];
            float av[4] = {a.x, a.y, a.z, a.w};
            float bv[8] = {b0.x, b0.y, b0.z, b0.w, b1f.x, b1f.y, b1f.z, b1f.w};
#pragma unroll
            for (int i = 0; i < 4; ++i)
#pragma unroll
                for (int j = 0; j < 8; ++j) acc[i][j] += av[i] * bv[j];
        }
    }

#pragma unroll
    for (int i = 0; i < 4; ++i)
#pragma unroll
        for (int j = 0; j < 8; ++j) T[ty * 8 + j][tx * 4 + i] = fmaxf(acc[i][j], 0.0f);

    float4 b2a = *(const float4*)(b2 + ty * 8);
    float4 b2b = *(const float4*)(b2 + ty * 8 + 4);
#pragma unroll
    for (int i = 0; i < 4; ++i) {
        acc[i][0] = b2a.x; acc[i][1] = b2a.y; acc[i][2] = b2a.z; acc[i][3] = b2a.w;
        acc[i][4] = b2b.x; acc[i][5] = b2b.y; acc[i][6] = b2b.z; acc[i][7] = b2b.w;
    }
    for (int cc = 0; cc < 4; ++cc) {
        __syncthreads();
        const float4* srcp = (const float4*)(W2 + (size_t)(cc * 32) * DD);
        float4* dstp = (float4*)&B[0][0];
#pragma unroll
        for (int r = 0; r < 4; ++r) dstp[t + r * 256] = srcp[t + r * 256];
        __syncthreads();
#pragma unroll 4
        for (int k = 0; k < 32; ++k) {
            float4 a  = *(const float4*)&T[cc * 32 + k][tx * 4];
            float4 b0 = *(const float4*)&B[k][ty * 8];
            float4 b1f = *(const float4*)&B[k][ty * 8 + 4];
            float av[4] = {a.x, a.y, a.z, a.w};
            float bv[8] = {b0.x, b0.y, b0.z, b0.w, b1f.x, b1f.y, b1f.z, b1f.w};
#pragma unroll
            for (int i = 0; i < 4; ++i)
#pragma unroll
                for (int j = 0; j < 8; ++j) acc[i][j] += av[i] * bv[j];
        }
    }

    __syncthreads();
#pragma unroll
    for (int i = 0; i < 4; ++i)
#pragma unroll
        for (int j = 0; j < 8; ++j) T[ty * 8 + j][tx * 4 + i] = acc[i][j];
    __syncthreads();

    if (t < TT) {
        int nd = i0 + t;
        if (nd < NND) {
            float* hrow = h + (size_t)nd * DD;
            float sum = 0.0f;
            for (int o = 0; o < DD; ++o) sum += T[o][t] + hrow[o];
            float mean = sum * (1.0f / DD);
            float var = 0.0f;
            for (int o = 0; o < DD; ++o) {
                float xv = T[o][t] + hrow[o] - mean;
                var += xv * xv;
            }
            var *= (1.0f / DD);
            float inv = 1.0f / sqrtf(var + 1e-5f);
            for (int o = 0; o < DD; ++o) {
                float xv = T[o][t] + hrow[o];
                hrow[o] = (xv - mean) * inv * lng[o] + lnb[o];
            }
        }
    }
}

// ---------------------------------------------------------------- pooling
__global__ __launch_bounds__(256) void cnt_kernel(
    const int* __restrict__ batch, float* __restrict__ cnt)
{
    int i = blockIdx.x * 256 + threadIdx.x;
    if (i >= NND) return;
    unsafeAtomicAdd(&cnt[batch[i]], 1.0f);
}

__global__ __launch_bounds__(256) void pool_kernel(
    const float* __restrict__ h, const int* __restrict__ batch, float* __restrict__ hs)
{
    int t = blockIdx.x * 256 + threadIdx.x;
    int i = t >> 7, d = t & 127;
    if (i >= NND) return;
    unsafeAtomicAdd(&hs[batch[i] * DD + d], h[(size_t)i * DD + d]);
}

// ---------------------------------------------------------------- decoder
__device__ __forceinline__ float softplus_stable(float y) {
    return fmaxf(y, 0.0f) + log1pf(expf(-fabsf(y)));
}

__global__ __launch_bounds__(256) void dec_kernel(
    const float* __restrict__ hs, const float* __restrict__ cnt,
    const float* __restrict__ W1, const float* __restrict__ b1,
    const float* __restrict__ lng, const float* __restrict__ lnb,
    const float* __restrict__ W2, const float* __restrict__ b2,
    const float* __restrict__ W3, const float* __restrict__ b3,
    float* __restrict__ out)
{
    int g  = blockIdx.x >> 1;
    int hd = blockIdx.x & 1;
    int t  = threadIdx.x;
    __shared__ float hg[DD];
    __shared__ float sA[256];
    __shared__ float red[256];

    if (t < DD) {
        float cct = fmaxf(cnt[g], 1.0f);
        hg[t] = hs[g * DD + t] / cct;
    }
    __syncthreads();

    const float* w1 = W1 + hd * DD * 256;
    float acc = b1[hd * 256 + t];
#pragma unroll 8
    for (int k = 0; k < DD; ++k) acc += hg[k] * w1[k * 256 + t];

    red[t] = acc; __syncthreads();
    for (int s = 128; s > 0; s >>= 1) { if (t < s) red[t] += red[t + s]; __syncthreads(); }
    float mean = red[0] * (1.0f / 256.0f);
    __syncthreads();
    float dv = acc - mean;
    red[t] = dv * dv; __syncthreads();
    for (int s = 128; s > 0; s >>= 1) { if (t < s) red[t] += red[t + s]; __syncthreads(); }
    float var = red[0] * (1.0f / 256.0f);
    float inv = 1.0f / sqrtf(var + 1e-5f);
    float z1 = dv * inv * lng[hd * 256 + t] + lnb[hd * 256 + t];
    z1 = softplus_stable(2.0f * z1) * 0.5f;
    __syncthreads();
    sA[t] = z1; __syncthreads();

    const float* w2 = W2 + hd * 256 * 256;
    float acc2 = b2[hd * 256 + t];
#pragma unroll 8
    for (int k = 0; k < 256; ++k) acc2 += sA[k] * w2[k * 256 + t];
    float z2 = softplus_stable(2.0f * acc2) * 0.5f;
    __syncthreads();
    sA[t] = z2; __syncthreads();

    const float* w3 = W3 + hd * 256 * 300;
    for (int s = t; s < 300; s += 256) {
        float acc3 = b3[hd * 300 + s];
#pragma unroll 8
        for (int k = 0; k < 256; ++k) acc3 += sA[k] * w3[k * 300 + s];
        out[g * 600 + hd * 300 + s] = softplus_stable(acc3);
    }
}

// ---------------------------------------------------------------- launch
extern "C" void kernel_launch(void* const* d_in, const int* in_sizes, int n_in,
                              void* d_out, int out_size, void* d_ws, size_t ws_size,
                              hipStream_t stream)
{
    const float* x     = (const float*)d_in[0];
    const float* pos   = (const float*)d_in[1];
    const float* eattr = (const float*)d_in[2];
    const int*   eidx  = (const int*)d_in[3];
    const int*   batch = (const int*)d_in[4];
    const float* W_in  = (const float*)d_in[5];
    const float* b_in  = (const float*)d_in[6];
    const float* msgW1 = (const float*)d_in[7];
    const float* msgb1 = (const float*)d_in[8];
    const float* msgW2 = (const float*)d_in[9];
    const float* msgb2 = (const float*)d_in[10];
    const float* updW1 = (const float*)d_in[11];
    const float* updb1 = (const float*)d_in[12];
    const float* updW2 = (const float*)d_in[13];
    const float* updb2 = (const float*)d_in[14];
    const float* lng   = (const float*)d_in[15];
    const float* lnb   = (const float*)d_in[16];
    const float* dW1   = (const float*)d_in[17];
    const float* db1   = (const float*)d_in[18];
    const float* dlng  = (const float*)d_in[19];
    const float* dlnb  = (const float*)d_in[20];
    const float* dW2   = (const float*)d_in[21];
    const float* db2   = (const float*)d_in[22];
    const float* dW3   = (const float*)d_in[23];
    const float* db3   = (const float*)d_in[24];

    float* ws  = (float*)d_ws;
    float* h    = ws;                   // N*128
    float* agg  = ws + 6400000;         // N*128
    float* d2   = ws + 12800000;        // E
    float* hsg  = ws + 13600000;        // G*128
    float* cnt  = ws + 13664000;        // G
    float* P    = ws + 13700000;        // 2*N*128
    int*   perm = (int*)(ws + 26500000);    // E
    int*   srcP = (int*)(ws + 27300000);    // E
    int*   dstP = (int*)(ws + 28100000);    // E
    float* eaP  = ws + 28900000;            // E*4
    int*   hist = (int*)(ws + 32100000);    // NHB
    int*   bsum = (int*)(ws + 32150176);    // 256
    int*   bsumx= (int*)(ws + 32150432);    // 256
    short* WP   = (short*)(ws + 32150688);  // 6*16384 bf16 pre-swizzled chunks

    const size_t need_sorted = (size_t)(32150688 + 49152) * 4;
    const bool sorted = (ws_size >= need_sorted);

    const int* srcI = eidx;
    const int* dstI = eidx + NE;

    inproj_kernel<<<25000, 256, 0, stream>>>(x, W_in, b_in, h);

    if (sorted) {
        hipMemsetAsync(hist, 0, (size_t)(NHB + 512) * 4, stream);
        hist_kernel<<<3125, 256, 0, stream>>>(dstI, hist);
        scan1_kernel<<<196, 256, 0, stream>>>(hist, bsum);
        scan2_kernel<<<1, 256, 0, stream>>>(bsum, bsumx);
        scan3_kernel<<<196, 256, 0, stream>>>(hist, bsumx);
        scatter_kernel<<<3125, 256, 0, stream>>>(dstI, hist, perm);
        permapply_kernel<<<3125, 256, 0, stream>>>(perm, srcI, dstI, eattr, srcP, dstP, eaP);
        d2p_kernel<<<3125, 256, 0, stream>>>(pos, srcP, dstP, d2);
    } else {
        d2_kernel<<<3125, 256, 0, stream>>>(pos, srcI, dstI, d2);
    }

    const int nblk_nodes = (NND + TT - 1) / TT;   // 782
    const int nblk_edges = NE / TT;               // 12500

    for (int l = 0; l < 4; ++l) {
        const float* W1l = msgW1 + (size_t)l * 261 * 128;
        hipMemsetAsync(agg, 0, 6400000 * sizeof(float), stream);
        if (sorted) {
            wprep_kernel<<<384, 256, 0, stream>>>(
                msgW2 + (size_t)l * 128 * 128, updW1 + (size_t)l * 256 * 128,
                updW2 + (size_t)l * 128 * 128, W1l, WP);
            projm_kernel<<<nblk_nodes, 256, 0, stream>>>(h, WP + 4 * 16384, WP + 5 * 16384, P);
            msgm_kernel<<<nblk_edges, 256, 0, stream>>>(P, srcP, dstP, eaP, d2,
                W1l + 256 * 128, msgb1 + l * 128, WP, msgb2 + l * 128, agg);
            updm_kernel<<<nblk_nodes, 256, 0, stream>>>(h, agg,
                WP + 1 * 16384, WP + 2 * 16384, WP + 3 * 16384,
                updb1 + l * 128, updb2 + l * 128, lng + l * 128, lnb + l * 128);
        } else {
            msgu_kernel<<<nblk_edges, 256, 0, stream>>>(h, srcI, dstI, eattr, d2,
                W1l, msgb1 + l * 128,
                msgW2 + (size_t)l * 128 * 128, msgb2 + l * 128, agg);
            updf_kernel<<<nblk_nodes, 256, 0, stream>>>(h, agg,
                updW1 + (size_t)l * 256 * 128, updb1 + l * 128,
                updW2 + (size_t)l * 128 * 128, updb2 + l * 128,
                lng + l * 128, lnb + l * 128);
        }
    }

    hipMemsetAsync(hsg, 0, 64500 * sizeof(float), stream);
    cnt_kernel<<<196, 256, 0, stream>>>(batch, cnt);
    pool_kernel<<<25000, 256, 0, stream>>>(h, batch, hsg);
    dec_kernel<<<1000, 256, 0, stream>>>(hsg, cnt, dW1, db1, dlng, dlnb,
                                         dW2, db2, dW3, db3, (float*)d_out);
}

// Round 10
// 1836.788 us; speedup vs baseline: 13.8999x; 1.0065x over previous
//
#include <hip/hip_runtime.h>
#include <cstdint>
#include <cstddef>

#define NND 50000
#define NE  800000
#define DD  128
#define NG  500
#define TT  64      // tile rows (edges/nodes) per block
#define NHB 50176   // hist size, padded to 196*256 exactly

typedef __attribute__((ext_vector_type(8))) short short8v;
typedef __attribute__((ext_vector_type(4))) float float4v;

// A-side LDS swizzle (updm/projm A tiles)
#define SWZA(row, g) ((g) ^ ((row) & 7) ^ (((row) >> 3) & 7))

// fp32 -> bf16 (RNE)
__device__ __forceinline__ short f2bf(float f) {
    unsigned u = __builtin_bit_cast(unsigned, f);
    unsigned r = (u + 0x7FFFu + ((u >> 16) & 1u)) >> 16;
    return (short)r;
}
__device__ __forceinline__ float bf2f(short s) {
    return __builtin_bit_cast(float, ((unsigned)(unsigned short)s) << 16);
}

// ---------------------------------------------------------------- input proj
__global__ __launch_bounds__(256) void inproj_kernel(
    const float* __restrict__ x, const float* __restrict__ W,
    const float* __restrict__ b, float* __restrict__ h)
{
    int t = blockIdx.x * 256 + threadIdx.x;
    int i = t >> 7, d = t & 127;
    if (i >= NND) return;
    const float* xr = x + (size_t)i * 11;
    float acc = b[d];
#pragma unroll
    for (int k = 0; k < 11; ++k) acc += xr[k] * W[k * DD + d];
    h[(size_t)i * DD + d] = acc;
}

// ---------------------------------------------------------------- counting sort by dst
__global__ __launch_bounds__(256) void hist_kernel(
    const int* __restrict__ dstI, int* __restrict__ hist)
{
    int e = blockIdx.x * 256 + threadIdx.x;
    if (e >= NE) return;
    atomicAdd(&hist[dstI[e]], 1);
}

__global__ __launch_bounds__(256) void scan1_kernel(
    int* __restrict__ hist, int* __restrict__ bsum)
{
    __shared__ int s[256];
    int tid = threadIdx.x;
    int i = blockIdx.x * 256 + tid;
    int v = hist[i];
    s[tid] = v; __syncthreads();
    for (int off = 1; off < 256; off <<= 1) {
        int tmp = (tid >= off) ? s[tid - off] : 0;
        __syncthreads();
        s[tid] += tmp;
        __syncthreads();
    }
    hist[i] = s[tid] - v;
    if (tid == 255) bsum[blockIdx.x] = s[255];
}

__global__ __launch_bounds__(256) void scan2_kernel(
    const int* __restrict__ bsum, int* __restrict__ bsumx)
{
    __shared__ int s[256];
    int tid = threadIdx.x;
    int v = (tid < 196) ? bsum[tid] : 0;
    s[tid] = v; __syncthreads();
    for (int off = 1; off < 256; off <<= 1) {
        int tmp = (tid >= off) ? s[tid - off] : 0;
        __syncthreads();
        s[tid] += tmp;
        __syncthreads();
    }
    if (tid < 196) bsumx[tid] = s[tid] - v;
}

__global__ __launch_bounds__(256) void scan3_kernel(
    int* __restrict__ hist, const int* __restrict__ bsumx)
{
    int i = blockIdx.x * 256 + threadIdx.x;
    hist[i] += bsumx[blockIdx.x];
}

__global__ __launch_bounds__(256) void scatter_kernel(
    const int* __restrict__ dstI, int* __restrict__ cursor, int* __restrict__ perm)
{
    int e = blockIdx.x * 256 + threadIdx.x;
    if (e >= NE) return;
    int pos = atomicAdd(&cursor[dstI[e]], 1);
    perm[pos] = e;
}

__global__ __launch_bounds__(256) void permapply_kernel(
    const int* __restrict__ perm, const int* __restrict__ srcI, const int* __restrict__ dstI,
    const float* __restrict__ ea,
    int* __restrict__ srcP, int* __restrict__ dstP, float* __restrict__ eaP)
{
    int i = blockIdx.x * 256 + threadIdx.x;
    if (i >= NE) return;
    int e = perm[i];
    srcP[i] = srcI[e];
    dstP[i] = dstI[e];
    ((float4*)eaP)[i] = ((const float4*)ea)[e];
}

__global__ __launch_bounds__(256) void d2p_kernel(
    const float* __restrict__ pos, const int* __restrict__ srcP,
    const int* __restrict__ dstP, float* __restrict__ d2)
{
    int e = blockIdx.x * 256 + threadIdx.x;
    if (e >= NE) return;
    int s = srcP[e], d = dstP[e];
    float dx = pos[d * 3 + 0] - pos[s * 3 + 0];
    float dy = pos[d * 3 + 1] - pos[s * 3 + 1];
    float dz = pos[d * 3 + 2] - pos[s * 3 + 2];
    d2[e] = dx * dx + dy * dy + dz * dz;
}

__global__ __launch_bounds__(256) void d2_kernel(
    const float* __restrict__ pos, const int* __restrict__ srcI,
    const int* __restrict__ dstI, float* __restrict__ d2)
{
    int e = blockIdx.x * 256 + threadIdx.x;
    if (e >= NE) return;
    int s = srcI[e], d = dstI[e];
    float dx = pos[d * 3 + 0] - pos[s * 3 + 0];
    float dy = pos[d * 3 + 1] - pos[s * 3 + 1];
    float dz = pos[d * 3 + 2] - pos[s * 3 + 2];
    d2[e] = dx * dx + dy * dy + dz * dz;
}

// ---------------------------------------------------------------- per-layer weight prep (6 chunks of [128][128], bf16 pre-swizzled)
__global__ __launch_bounds__(256) void wprep_kernel(
    const float* __restrict__ msgW2, const float* __restrict__ updW1,
    const float* __restrict__ updW2, const float* __restrict__ msgW1,
    short* __restrict__ out)
{
    int p = blockIdx.x * 256 + threadIdx.x;   // grid 384 -> 98304
    int chunk = p >> 14;
    int idx = p & 16383;
    int n = idx >> 7;
    int q = (idx & 127) >> 3;
    int j = idx & 7;
    int k = (q ^ (n & 7)) * 8 + j;
    const float* src;
    if      (chunk == 0) src = msgW2;
    else if (chunk == 1) src = updW1;
    else if (chunk == 2) src = updW1 + 128 * DD;
    else if (chunk == 3) src = updW2;
    else if (chunk == 4) src = msgW1;
    else                 src = msgW1 + 128 * DD;
    out[p] = f2bf(src[k * DD + n]);
}

// ---------------------------------------------------------------- MFMA node projections -> bf16 P
__global__ __launch_bounds__(256, 3) void projm_kernel(
    const float* __restrict__ h, const short* __restrict__ Wa, const short* __restrict__ Wb,
    short* __restrict__ P)
{
    __shared__ __align__(16) short A[64 * 128];    // 16 KB
    __shared__ __align__(16) short W[128 * 128];   // 32 KB
    int t = threadIdx.x;
    int i0 = blockIdx.x * TT;

    {
        int e = t >> 2;
        int node = i0 + e; if (node >= NND) node = NND - 1;
        const float* hr = h + (size_t)node * DD;
#pragma unroll
        for (int j = 0; j < 4; ++j) {
            int g = (t & 3) * 4 + j;
            float4 v0 = *(const float4*)(hr + g * 8);
            float4 v1 = *(const float4*)(hr + g * 8 + 4);
            short8v pk;
            pk[0]=f2bf(v0.x); pk[1]=f2bf(v0.y); pk[2]=f2bf(v0.z); pk[3]=f2bf(v0.w);
            pk[4]=f2bf(v1.x); pk[5]=f2bf(v1.y); pk[6]=f2bf(v1.z); pk[7]=f2bf(v1.w);
            *(short8v*)&A[e * 128 + SWZA(e, g) * 8] = pk;
        }
    }
    {
        const short8v* g = (const short8v*)Wa;
        short8v* l = (short8v*)W;
#pragma unroll
        for (int p = 0; p < 8; ++p) l[t + p * 256] = g[t + p * 256];
    }
    __syncthreads();

    int lane = t & 63, w = t >> 6;
    int c = lane & 15, lg = lane >> 4;
    int m = w * 16 + c;

    for (int mat = 0; mat < 2; ++mat) {
        float4v acc[8];
#pragma unroll
        for (int i = 0; i < 8; ++i) acc[i] = (float4v){0.f, 0.f, 0.f, 0.f};
#pragma unroll
        for (int ks = 0; ks < 4; ++ks) {
            int kg = ks * 4 + lg;
            short8v afrag = *(const short8v*)&A[m * 128 + SWZA(m, kg) * 8];
#pragma unroll
            for (int nt = 0; nt < 8; ++nt) {
                int n = nt * 16 + c;
                short8v bfrag = *(const short8v*)&W[n * 128 + ((kg ^ (n & 7)) << 3)];
                acc[nt] = __builtin_amdgcn_mfma_f32_16x16x32_bf16(afrag, bfrag, acc[nt], 0, 0, 0);
            }
        }
        short* out = P + (size_t)mat * NND * DD;
#pragma unroll
        for (int reg = 0; reg < 4; ++reg) {
            int node = i0 + w * 16 + lg * 4 + reg;
            if (node < NND) {
#pragma unroll
                for (int nt = 0; nt < 8; ++nt)
                    out[(size_t)node * DD + nt * 16 + c] = f2bf(acc[nt][reg]);
            }
        }
        if (mat == 0) {
            __syncthreads();
            const short8v* g = (const short8v*)Wb;
            short8v* l = (short8v*)W;
#pragma unroll
            for (int p = 0; p < 8; ++p) l[t + p * 256] = g[t + p * 256];
            __syncthreads();
        }
    }
}

// ---------------------------------------------------------------- message: producer=consumer lanes, bf16 P, no T LDS
__global__ __launch_bounds__(256, 4) void msgm_kernel(
    const short* __restrict__ P, const int* __restrict__ srcP, const int* __restrict__ dstP,
    const float* __restrict__ eaP, const float* __restrict__ d2,
    const float* __restrict__ W1tail, const float* __restrict__ b1,
    const short* __restrict__ W2t, const float* __restrict__ b2,
    float* __restrict__ agg)
{
    __shared__ __align__(16) short W2ld[128 * 128];   // 32 KB (pre-swizzled bf16)
    __shared__ __align__(16) float WcB[6 * 128];      // 3 KB: rows 0..4 = Wc, row 5 = b1
    int t = threadIdx.x;
    int e0 = blockIdx.x * TT;

    {
        const short8v* g = (const short8v*)W2t;
        short8v* l = (short8v*)W2ld;
#pragma unroll
        for (int p = 0; p < 8; ++p) l[t + p * 256] = g[t + p * 256];
        if (t < 160)      ((float4*)WcB)[t] = ((const float4*)W1tail)[t];
        else if (t < 192) ((float4*)WcB)[t] = ((const float4*)b1)[t - 160];
    }
    __syncthreads();

    int lane = t & 63, w = t >> 6;
    int c = lane & 15, lg = lane >> 4;
    int e = e0 + w * 16 + c;
    int ds = dstP[e], sr = srcP[e];
    const short* pd = P + (size_t)ds * DD;
    const short* ps = P + (size_t)NND * DD + (size_t)sr * DD;
    float4 av = ((const float4*)eaP)[e];
    float ev[5] = {av.x, av.y, av.z, av.w, d2[e]};

    short8v afrag[4];
#pragma unroll
    for (int ks = 0; ks < 4; ++ks) {
        int kg = ks * 4 + lg;
        short8v pdv = *(const short8v*)(pd + kg * 8);
        short8v psv = *(const short8v*)(ps + kg * 8);
        float tv[8];
#pragma unroll
        for (int j = 0; j < 8; ++j)
            tv[j] = bf2f(pdv[j]) + bf2f(psv[j]) + WcB[5 * 128 + kg * 8 + j];
#pragma unroll
        for (int qf = 0; qf < 5; ++qf) {
            float xx = ev[qf];
#pragma unroll
            for (int j = 0; j < 8; ++j) tv[j] += xx * WcB[qf * 128 + kg * 8 + j];
        }
        short8v pk;
#pragma unroll
        for (int j = 0; j < 8; ++j) pk[j] = f2bf(fmaxf(tv[j], 0.0f));
        afrag[ks] = pk;
    }

    float4v acc[8];
#pragma unroll
    for (int i = 0; i < 8; ++i) acc[i] = (float4v){0.f, 0.f, 0.f, 0.f};
#pragma unroll
    for (int ks = 0; ks < 4; ++ks) {
        int kg = ks * 4 + lg;
#pragma unroll
        for (int nt = 0; nt < 8; ++nt) {
            int n = nt * 16 + c;
            short8v bfrag = *(const short8v*)&W2ld[n * 128 + ((kg ^ (n & 7)) << 3)];
            acc[nt] = __builtin_amdgcn_mfma_f32_16x16x32_bf16(afrag[ks], bfrag, acc[nt], 0, 0, 0);
        }
    }

    // epilogue: D row = w*16 + lg*4 + reg, col = nt*16 + c; merged atomics over sorted dst
    int base_e = e0 + w * 16 + (lg << 2);
    int4 dq = *(const int4*)(dstP + base_e);
    int drow[4] = {dq.x, dq.y, dq.z, dq.w};
    float b2c[8];
#pragma unroll
    for (int nt = 0; nt < 8; ++nt) b2c[nt] = b2[nt * 16 + c];

    float sum[8];
    int cur = drow[0];
#pragma unroll
    for (int nt = 0; nt < 8; ++nt) sum[nt] = acc[nt][0] + b2c[nt];
#pragma unroll
    for (int r = 1; r < 4; ++r) {
        if (drow[r] == cur) {
#pragma unroll
            for (int nt = 0; nt < 8; ++nt) sum[nt] += acc[nt][r] + b2c[nt];
        } else {
            float* ag = agg + (size_t)cur * DD + c;
#pragma unroll
            for (int nt = 0; nt < 8; ++nt) unsafeAtomicAdd(ag + nt * 16, sum[nt]);
            cur = drow[r];
#pragma unroll
            for (int nt = 0; nt < 8; ++nt) sum[nt] = acc[nt][r] + b2c[nt];
        }
    }
    float* ag = agg + (size_t)cur * DD + c;
#pragma unroll
    for (int nt = 0; nt < 8; ++nt) unsafeAtomicAdd(ag + nt * 16, sum[nt]);
}

// ---------------------------------------------------------------- MFMA node update + residual + LN
__global__ __launch_bounds__(256, 3) void updm_kernel(
    float* __restrict__ h, const float* __restrict__ agg,
    const short* __restrict__ W1a, const short* __restrict__ W1b, const short* __restrict__ W2s,
    const float* __restrict__ b1, const float* __restrict__ b2,
    const float* __restrict__ lng, const float* __restrict__ lnb)
{
    __shared__ __align__(16) short A[64 * 128];    // 16 KB
    __shared__ __align__(16) short W[128 * 128];   // 32 KB
    int t = threadIdx.x;
    int i0 = blockIdx.x * TT;
    int lane = t & 63, w = t >> 6;
    int c = lane & 15, lg = lane >> 4;
    int m = w * 16 + c;

    {
        int e = t >> 2;
        int node = i0 + e; if (node >= NND) node = NND - 1;
        const float* hr = h + (size_t)node * DD;
#pragma unroll
        for (int j = 0; j < 4; ++j) {
            int g = (t & 3) * 4 + j;
            float4 v0 = *(const float4*)(hr + g * 8);
            float4 v1 = *(const float4*)(hr + g * 8 + 4);
            short8v pk;
            pk[0]=f2bf(v0.x); pk[1]=f2bf(v0.y); pk[2]=f2bf(v0.z); pk[3]=f2bf(v0.w);
            pk[4]=f2bf(v1.x); pk[5]=f2bf(v1.y); pk[6]=f2bf(v1.z); pk[7]=f2bf(v1.w);
            *(short8v*)&A[e * 128 + SWZA(e, g) * 8] = pk;
        }
        const short8v* gg = (const short8v*)W1a;
        short8v* l = (short8v*)W;
#pragma unroll
        for (int p = 0; p < 8; ++p) l[t + p * 256] = gg[t + p * 256];
    }
    __syncthreads();

    float4v acc[8];
#pragma unroll
    for (int i = 0; i < 8; ++i) acc[i] = (float4v){0.f, 0.f, 0.f, 0.f};

#pragma unroll
    for (int ks = 0; ks < 4; ++ks) {
        int kg = ks * 4 + lg;
        short8v afrag = *(const short8v*)&A[m * 128 + SWZA(m, kg) * 8];
#pragma unroll
        for (int nt = 0; nt < 8; ++nt) {
            int n = nt * 16 + c;
            short8v bfrag = *(const short8v*)&W[n * 128 + ((kg ^ (n & 7)) << 3)];
            acc[nt] = __builtin_amdgcn_mfma_f32_16x16x32_bf16(afrag, bfrag, acc[nt], 0, 0, 0);
        }
    }
    __syncthreads();

    {
        int e = t >> 2;
        int node = i0 + e; if (node >= NND) node = NND - 1;
        const float* ar = agg + (size_t)node * DD;
#pragma unroll
        for (int j = 0; j < 4; ++j) {
            int g = (t & 3) * 4 + j;
            float4 v0 = *(const float4*)(ar + g * 8);
            float4 v1 = *(const float4*)(ar + g * 8 + 4);
            short8v pk;
            pk[0]=f2bf(v0.x); pk[1]=f2bf(v0.y); pk[2]=f2bf(v0.z); pk[3]=f2bf(v0.w);
            pk[4]=f2bf(v1.x); pk[5]=f2bf(v1.y); pk[6]=f2bf(v1.z); pk[7]=f2bf(v1.w);
            *(short8v*)&A[e * 128 + SWZA(e, g) * 8] = pk;
        }
        const short8v* gg = (const short8v*)W1b;
        short8v* l = (short8v*)W;
#pragma unroll
        for (int p = 0; p < 8; ++p) l[t + p * 256] = gg[t + p * 256];
    }
    __syncthreads();

#pragma unroll
    for (int ks = 0; ks < 4; ++ks) {
        int kg = ks * 4 + lg;
        short8v afrag = *(const short8v*)&A[m * 128 + SWZA(m, kg) * 8];
#pragma unroll
        for (int nt = 0; nt < 8; ++nt) {
            int n = nt * 16 + c;
            short8v bfrag = *(const short8v*)&W[n * 128 + ((kg ^ (n & 7)) << 3)];
            acc[nt] = __builtin_amdgcn_mfma_f32_16x16x32_bf16(afrag, bfrag, acc[nt], 0, 0, 0);
        }
    }
    __syncthreads();

    {
        float b1c[8];
#pragma unroll
        for (int nt = 0; nt < 8; ++nt) b1c[nt] = b1[nt * 16 + c];
#pragma unroll
        for (int reg = 0; reg < 4; ++reg) {
            int rowT = w * 16 + lg * 4 + reg;
#pragma unroll
            for (int nt = 0; nt < 8; ++nt) {
                int col = nt * 16 + c;
                int colg = col >> 3;
                float v = fmaxf(acc[nt][reg] + b1c[nt], 0.0f);
                A[rowT * 128 + SWZA(rowT, colg) * 8 + (col & 7)] = f2bf(v);
            }
        }
        const short8v* gg = (const short8v*)W2s;
        short8v* l = (short8v*)W;
#pragma unroll
        for (int p = 0; p < 8; ++p) l[t + p * 256] = gg[t + p * 256];
    }
    __syncthreads();

#pragma unroll
    for (int i = 0; i < 8; ++i) acc[i] = (float4v){0.f, 0.f, 0.f, 0.f};
#pragma unroll
    for (int ks = 0; ks < 4; ++ks) {
        int kg = ks * 4 + lg;
        short8v afrag = *(const short8v*)&A[m * 128 + SWZA(m, kg) * 8];
#pragma unroll
        for (int nt = 0; nt < 8; ++nt) {
            int n = nt * 16 + c;
            short8v bfrag = *(const short8v*)&W[n * 128 + ((kg ^ (n & 7)) << 3)];
            acc[nt] = __builtin_amdgcn_mfma_f32_16x16x32_bf16(afrag, bfrag, acc[nt], 0, 0, 0);
        }
    }

    float b2c[8], lngc[8], lnbc[8];
#pragma unroll
    for (int nt = 0; nt < 8; ++nt) {
        b2c[nt]  = b2[nt * 16 + c];
        lngc[nt] = lng[nt * 16 + c];
        lnbc[nt] = lnb[nt * 16 + c];
    }
    float xx[8][4];
#pragma unroll
    for (int reg = 0; reg < 4; ++reg) {
        int node = i0 + w * 16 + lg * 4 + reg;
        int nclamp = (node < NND) ? node : (NND - 1);
        const float* hr = h + (size_t)nclamp * DD;
#pragma unroll
        for (int nt = 0; nt < 8; ++nt)
            xx[nt][reg] = acc[nt][reg] + b2c[nt] + hr[nt * 16 + c];
    }
    float s[4] = {0.f, 0.f, 0.f, 0.f};
#pragma unroll
    for (int reg = 0; reg < 4; ++reg)
#pragma unroll
        for (int nt = 0; nt < 8; ++nt) s[reg] += xx[nt][reg];
#pragma unroll
    for (int msk = 1; msk < 16; msk <<= 1)
#pragma unroll
        for (int reg = 0; reg < 4; ++reg) s[reg] += __shfl_xor(s[reg], msk, 64);
    float mean[4];
#pragma unroll
    for (int reg = 0; reg < 4; ++reg) mean[reg] = s[reg] * (1.0f / DD);
    float v[4] = {0.f, 0.f, 0.f, 0.f};
#pragma unroll
    for (int reg = 0; reg < 4; ++reg)
#pragma unroll
        for (int nt = 0; nt < 8; ++nt) {
            float dv = xx[nt][reg] - mean[reg];
            v[reg] += dv * dv;
        }
#pragma unroll
    for (int msk = 1; msk < 16; msk <<= 1)
#pragma unroll
        for (int reg = 0; reg < 4; ++reg) v[reg] += __shfl_xor(v[reg], msk, 64);
#pragma unroll
    for (int reg = 0; reg < 4; ++reg) {
        int node = i0 + w * 16 + lg * 4 + reg;
        if (node < NND) {
            float inv = 1.0f / sqrtf(v[reg] * (1.0f / DD) + 1e-5f);
            float* hw = h + (size_t)node * DD;
#pragma unroll
            for (int nt = 0; nt < 8; ++nt)
                hw[nt * 16 + c] = (xx[nt][reg] - mean[reg]) * inv * lngc[nt] + lnbc[nt];
        }
    }
}

// ---------------------------------------------------------------- fallback: unfactored fp32 message (K=261)
__global__ __launch_bounds__(256, 2) void msgu_kernel(
    const float* __restrict__ h, const int* __restrict__ srcI, const int* __restrict__ dstI,
    const float* __restrict__ ea, const float* __restrict__ d2,
    const float* __restrict__ W1, const float* __restrict__ b1,
    const float* __restrict__ W2, const float* __restrict__ b2,
    float* __restrict__ agg)
{
    __shared__ __align__(16) float A[32][TT];
    __shared__ __align__(16) float T[DD][TT];
    __shared__ __align__(16) float B[32][DD];
    int t = threadIdx.x;
    int e0 = blockIdx.x * TT;
    int tx = t & 15, ty = t >> 4;
    int e = t & 63, q = t >> 6;
    int dn = dstI[e0 + e], sn = srcI[e0 + e];

    float4 b1a = *(const float4*)(b1 + ty * 8);
    float4 b1b = *(const float4*)(b1 + ty * 8 + 4);
    float acc[4][8];
#pragma unroll
    for (int i = 0; i < 4; ++i) {
        acc[i][0] = b1a.x; acc[i][1] = b1a.y; acc[i][2] = b1a.z; acc[i][3] = b1a.w;
        acc[i][4] = b1b.x; acc[i][5] = b1b.y; acc[i][6] = b1b.z; acc[i][7] = b1b.w;
    }

    for (int cc = 0; cc < 9; ++cc) {
        int kmax = (cc == 8) ? 5 : 32;
        __syncthreads();
        if (cc < 8) {
            const float* row = h + (size_t)((cc < 4) ? dn : sn) * DD + (cc & 3) * 32;
            float4 v0 = *(const float4*)(row + q * 8);
            float4 v1 = *(const float4*)(row + q * 8 + 4);
#pragma unroll
            for (int j = 0; j < 4; ++j) A[q * 8 + j][e]     = (&v0.x)[j];
#pragma unroll
            for (int j = 0; j < 4; ++j) A[q * 8 + 4 + j][e] = (&v1.x)[j];
        } else if (t < TT) {
            float4 av = ((const float4*)ea)[e0 + t];
            A[0][t] = av.x; A[1][t] = av.y; A[2][t] = av.z; A[3][t] = av.w;
            A[4][t] = d2[e0 + t];
        }
        const float4* srcp = (const float4*)(W1 + (size_t)(cc * 32) * DD);
        float4* dstp = (float4*)&B[0][0];
        if (cc < 8) {
#pragma unroll
            for (int r = 0; r < 4; ++r) dstp[t + r * 256] = srcp[t + r * 256];
        } else if (t < 160) {
            dstp[t] = srcp[t];
        }
        __syncthreads();
        for (int k = 0; k < kmax; ++k) {
            float4 a  = *(const float4*)&A[k][tx * 4];
            float4 b0 = *(const float4*)&B[k][ty * 8];
            float4 b1f = *(const float4*)&B[k][ty * 8 + 4];
            float av[4] = {a.x, a.y, a.z, a.w};
            float bv[8] = {b0.x, b0.y, b0.z, b0.w, b1f.x, b1f.y, b1f.z, b1f.w};
#pragma unroll
            for (int i = 0; i < 4; ++i)
#pragma unroll
                for (int j = 0; j < 8; ++j) acc[i][j] += av[i] * bv[j];
        }
    }

#pragma unroll
    for (int i = 0; i < 4; ++i)
#pragma unroll
        for (int j = 0; j < 8; ++j) T[ty * 8 + j][tx * 4 + i] = fmaxf(acc[i][j], 0.0f);

    float4 b2a = *(const float4*)(b2 + ty * 8);
    float4 b2b = *(const float4*)(b2 + ty * 8 + 4);
#pragma unroll
    for (int i = 0; i < 4; ++i) {
        acc[i][0] = b2a.x; acc[i][1] = b2a.y; acc[i][2] = b2a.z; acc[i][3] = b2a.w;
        acc[i][4] = b2b.x; acc[i][5] = b2b.y; acc[i][6] = b2b.z; acc[i][7] = b2b.w;
    }
    for (int cc = 0; cc < 4; ++cc) {
        __syncthreads();
        const float4* srcp = (const float4*)(W2 + (size_t)(cc * 32) * DD);
        float4* dstp = (float4*)&B[0][0];
#pragma unroll
        for (int r = 0; r < 4; ++r) dstp[t + r * 256] = srcp[t + r * 256];
        __syncthreads();
#pragma unroll 4
        for (int k = 0; k < 32; ++k) {
            float4 a  = *(const float4*)&T[cc * 32 + k][tx * 4];
            float4 b0 = *(const float4*)&B[k][ty * 8];
            float4 b1f = *(const float4*)&B[k][ty * 8 + 4];
            float av[4] = {a.x, a.y, a.z, a.w};
            float bv[8] = {b0.x, b0.y, b0.z, b0.w, b1f.x, b1f.y, b1f.z, b1f.w};
#pragma unroll
            for (int i = 0; i < 4; ++i)
#pragma unroll
                for (int j = 0; j < 8; ++j) acc[i][j] += av[i] * bv[j];
        }
    }
#pragma unroll
    for (int i = 0; i < 4; ++i) {
        int d = dstI[e0 + tx * 4 + i];
        float* ag = agg + (size_t)d * DD + ty * 8;
#pragma unroll
        for (int j = 0; j < 8; ++j) unsafeAtomicAdd(ag + j, acc[i][j]);
    }
}

// ---------------------------------------------------------------- fallback: fp32 node update
__global__ __launch_bounds__(256, 2) void updf_kernel(
    float* __restrict__ h, const float* __restrict__ agg,
    const float* __restrict__ W1, const float* __restrict__ b1,
    const float* __restrict__ W2, const float* __restrict__ b2,
    const float* __restrict__ lng, const float* __restrict__ lnb)
{
    __shared__ __align__(16) float A[32][TT];
    __shared__ __align__(16) float T[DD][TT];
    __shared__ __align__(16) float B[32][DD];
    int t = threadIdx.x;
    int i0 = blockIdx.x * TT;
    int tx = t & 15, ty = t >> 4;
    int e = t & 63, q = t >> 6;
    int node = i0 + e; int nclamp = (node < NND) ? node : (NND - 1);

    float4 b1a = *(const float4*)(b1 + ty * 8);
    float4 b1b = *(const float4*)(b1 + ty * 8 + 4);
    float acc[4][8];
#pragma unroll
    for (int i = 0; i < 4; ++i) {
        acc[i][0] = b1a.x; acc[i][1] = b1a.y; acc[i][2] = b1a.z; acc[i][3] = b1a.w;
        acc[i][4] = b1b.x; acc[i][5] = b1b.y; acc[i][6] = b1b.z; acc[i][7] = b1b.w;
    }

    for (int cc = 0; cc < 8; ++cc) {
        __syncthreads();
        const float* row = ((cc < 4) ? (h + (size_t)nclamp * DD + cc * 32)
                                     : (agg + (size_t)nclamp * DD + (cc - 4) * 32));
        float4 v0 = *(const float4*)(row + q * 8);
        float4 v1 = *(const float4*)(row + q * 8 + 4);
#pragma unroll
        for (int j = 0; j < 4; ++j) A[q * 8 + j][e]     = (&v0.x)[j];
#pragma unroll
        for (int j = 0; j < 4; ++j) A[q * 8 + 4 + j][e] = (&v1.x)[j];
        const float4* srcp = (const float4*)(W1 + (size_t)(cc * 32) * DD);
        float4* dstp = (float4*)&B[0][0];
#pragma unroll
        for (int r = 0; r < 4; ++r) dstp[t + r * 256] = srcp[t + r * 256];
        __syncthreads();
#pragma unroll 4
        for (int k = 0; k < 32; ++k) {
            float4 a  = *(const float4*)&A[k][tx * 4];
            float4 b0 = *(const float4*)&B[k][ty * 8];
            float4 b1f = *(const float4*)&B[k][ty * 8 + 4];
            float av[4] = {a.x, a.y, a.z, a.w};
            float bv[8] = {b0.x, b0.y, b0.z, b0.w, b1f.x, b1f.y, b1f.z, b1f.w};
#pragma unroll
            for (int i = 0; i < 4; ++i)
#pragma unroll
                for (int j = 0; j < 8; ++j) acc[i][j] += av[i] * bv[j];
        }
    }

#pragma unroll
    for (int i = 0; i < 4; ++i)
#pragma unroll
        for (int j = 0; j < 8; ++j) T[ty * 8 + j][tx * 4 + i] = fmaxf(acc[i][j], 0.0f);

    float4 b2a = *(const float4*)(b2 + ty * 8);
    float4 b2b = *(const float4*)(b2 + ty * 8 + 4);
#pragma unroll
    for (int i = 0; i < 4; ++i) {
        acc[i][0] = b2a.x; acc[i][1] = b2a.y; acc[i][2] = b2a.z; acc[i][3] = b2a.w;
        acc[i][4] = b2b.x; acc[i][5] = b2b.y; acc[i][6] = b2b.z; acc[i][7] = b2b.w;
    }
    for (int cc = 0; cc < 4; ++cc) {
        __syncthreads();
        const float4* srcp = (const float4*)(W2 + (size_t)(cc * 32) * DD);
        float4* dstp = (float4*)&B[0][0];
#pragma unroll
        for (int r = 0; r < 4; ++r) dstp[t + r * 256] = srcp[t + r * 256];
        __syncthreads();
#pragma unroll 4
        for (int k = 0; k < 32; ++k) {
            float4 a  = *(const float4*)&T[cc * 32 + k][tx * 4];
            float4 b0 = *(const float4*)&B[k][ty * 8];
            float4 b1f = *(const float4*)&B[k][ty * 8 + 4];
            float av[4] = {a.x, a.y, a.z, a.w};
            float bv[8] = {b0.x, b0.y, b0.z, b0.w, b1f.x, b1f.y, b1f.z, b1f.w};
#pragma unroll
            for (int i = 0; i < 4; ++i)
#pragma unroll
                for (int j = 0; j < 8; ++j) acc[i][j] += av[i] * bv[j];
        }
    }

    __syncthreads();
#pragma unroll
    for (int i = 0; i < 4; ++i)
#pragma unroll
        for (int j = 0; j < 8; ++j) T[ty * 8 + j][tx * 4 + i] = acc[i][j];
    __syncthreads();

    if (t < TT) {
        int nd = i0 + t;
        if (nd < NND) {
            float* hrow = h + (size_t)nd * DD;
            float sum = 0.0f;
            for (int o = 0; o < DD; ++o) sum += T[o][t] + hrow[o];
            float mean = sum * (1.0f / DD);
            float var = 0.0f;
            for (int o = 0; o < DD; ++o) {
                float xv = T[o][t] + hrow[o] - mean;
                var += xv * xv;
            }
            var *= (1.0f / DD);
            float inv = 1.0f / sqrtf(var + 1e-5f);
            for (int o = 0; o < DD; ++o) {
                float xv = T[o][t] + hrow[o];
                hrow[o] = (xv - mean) * inv * lng[o] + lnb[o];
            }
        }
    }
}

// ---------------------------------------------------------------- pooling
__global__ __launch_bounds__(256) void cnt_kernel(
    const int* __restrict__ batch, float* __restrict__ cnt)
{
    int i = blockIdx.x * 256 + threadIdx.x;
    if (i >= NND) return;
    unsafeAtomicAdd(&cnt[batch[i]], 1.0f);
}

__global__ __launch_bounds__(256) void pool_kernel(
    const float* __restrict__ h, const int* __restrict__ batch, float* __restrict__ hs)
{
    int t = blockIdx.x * 256 + threadIdx.x;
    int i = t >> 7, d = t & 127;
    if (i >= NND) return;
    unsafeAtomicAdd(&hs[batch[i] * DD + d], h[(size_t)i * DD + d]);
}

// ---------------------------------------------------------------- decoder
__device__ __forceinline__ float softplus_stable(float y) {
    return fmaxf(y, 0.0f) + log1pf(expf(-fabsf(y)));
}

__global__ __launch_bounds__(256) void dec_kernel(
    const float* __restrict__ hs, const float* __restrict__ cnt,
    const float* __restrict__ W1, const float* __restrict__ b1,
    const float* __restrict__ lng, const float* __restrict__ lnb,
    const float* __restrict__ W2, const float* __restrict__ b2,
    const float* __restrict__ W3, const float* __restrict__ b3,
    float* __restrict__ out)
{
    int g  = blockIdx.x >> 1;
    int hd = blockIdx.x & 1;
    int t  = threadIdx.x;
    __shared__ float hg[DD];
    __shared__ float sA[256];
    __shared__ float red[256];

    if (t < DD) {
        float cct = fmaxf(cnt[g], 1.0f);
        hg[t] = hs[g * DD + t] / cct;
    }
    __syncthreads();

    const float* w1 = W1 + hd * DD * 256;
    float acc = b1[hd * 256 + t];
#pragma unroll 8
    for (int k = 0; k < DD; ++k) acc += hg[k] * w1[k * 256 + t];

    red[t] = acc; __syncthreads();
    for (int s = 128; s > 0; s >>= 1) { if (t < s) red[t] += red[t + s]; __syncthreads(); }
    float mean = red[0] * (1.0f / 256.0f);
    __syncthreads();
    float dv = acc - mean;
    red[t] = dv * dv; __syncthreads();
    for (int s = 128; s > 0; s >>= 1) { if (t < s) red[t] += red[t + s]; __syncthreads(); }
    float var = red[0] * (1.0f / 256.0f);
    float inv = 1.0f / sqrtf(var + 1e-5f);
    float z1 = dv * inv * lng[hd * 256 + t] + lnb[hd * 256 + t];
    z1 = softplus_stable(2.0f * z1) * 0.5f;
    __syncthreads();
    sA[t] = z1; __syncthreads();

    const float* w2 = W2 + hd * 256 * 256;
    float acc2 = b2[hd * 256 + t];
#pragma unroll 8
    for (int k = 0; k < 256; ++k) acc2 += sA[k] * w2[k * 256 + t];
    float z2 = softplus_stable(2.0f * acc2) * 0.5f;
    __syncthreads();
    sA[t] = z2; __syncthreads();

    const float* w3 = W3 + hd * 256 * 300;
    for (int s = t; s < 300; s += 256) {
        float acc3 = b3[hd * 300 + s];
#pragma unroll 8
        for (int k = 0; k < 256; ++k) acc3 += sA[k] * w3[k * 300 + s];
        out[g * 600 + hd * 300 + s] = softplus_stable(acc3);
    }
}

// ---------------------------------------------------------------- launch
extern "C" void kernel_launch(void* const* d_in, const int* in_sizes, int n_in,
                              void* d_out, int out_size, void* d_ws, size_t ws_size,
                              hipStream_t stream)
{
    const float* x     = (const float*)d_in[0];
    const float* pos   = (const float*)d_in[1];
    const float* eattr = (const float*)d_in[2];
    const int*   eidx  = (const int*)d_in[3];
    const int*   batch = (const int*)d_in[4];
    const float* W_in  = (const float*)d_in[5];
    const float* b_in  = (const float*)d_in[6];
    const float* msgW1 = (const float*)d_in[7];
    const float* msgb1 = (const float*)d_in[8];
    const float* msgW2 = (const float*)d_in[9];
    const float* msgb2 = (const float*)d_in[10];
    const float* updW1 = (const float*)d_in[11];
    const float* updb1 = (const float*)d_in[12];
    const float* updW2 = (const float*)d_in[13];
    const float* updb2 = (const float*)d_in[14];
    const float* lng   = (const float*)d_in[15];
    const float* lnb   = (const float*)d_in[16];
    const float* dW1   = (const float*)d_in[17];
    const float* db1   = (const float*)d_in[18];
    const float* dlng  = (const float*)d_in[19];
    const float* dlnb  = (const float*)d_in[20];
    const float* dW2   = (const float*)d_in[21];
    const float* db2   = (const float*)d_in[22];
    const float* dW3   = (const float*)d_in[23];
    const float* db3   = (const float*)d_in[24];

    float* ws  = (float*)d_ws;
    float* h    = ws;                   // N*128
    float* agg  = ws + 6400000;         // N*128
    float* d2   = ws + 12800000;        // E
    float* hsg  = ws + 13600000;        // G*128
    float* cnt  = ws + 13664000;        // G
    short* P    = (short*)(ws + 13700000);  // 2*N*128 bf16
    int*   perm = (int*)(ws + 26500000);    // E
    int*   srcP = (int*)(ws + 27300000);    // E
    int*   dstP = (int*)(ws + 28100000);    // E
    float* eaP  = ws + 28900000;            // E*4
    int*   hist = (int*)(ws + 32100000);    // NHB
    int*   bsum = (int*)(ws + 32150176);    // 256
    int*   bsumx= (int*)(ws + 32150432);    // 256
    short* WP   = (short*)(ws + 32150688);  // 6*16384 bf16 pre-swizzled chunks

    const size_t need_sorted = (size_t)(32150688 + 49152) * 4;
    const bool sorted = (ws_size >= need_sorted);

    const int* srcI = eidx;
    const int* dstI = eidx + NE;

    inproj_kernel<<<25000, 256, 0, stream>>>(x, W_in, b_in, h);

    if (sorted) {
        hipMemsetAsync(hist, 0, (size_t)(NHB + 512) * 4, stream);
        hist_kernel<<<3125, 256, 0, stream>>>(dstI, hist);
        scan1_kernel<<<196, 256, 0, stream>>>(hist, bsum);
        scan2_kernel<<<1, 256, 0, stream>>>(bsum, bsumx);
        scan3_kernel<<<196, 256, 0, stream>>>(hist, bsumx);
        scatter_kernel<<<3125, 256, 0, stream>>>(dstI, hist, perm);
        permapply_kernel<<<3125, 256, 0, stream>>>(perm, srcI, dstI, eattr, srcP, dstP, eaP);
        d2p_kernel<<<3125, 256, 0, stream>>>(pos, srcP, dstP, d2);
    } else {
        d2_kernel<<<3125, 256, 0, stream>>>(pos, srcI, dstI, d2);
    }

    const int nblk_nodes = (NND + TT - 1) / TT;   // 782
    const int nblk_edges = NE / TT;               // 12500

    for (int l = 0; l < 4; ++l) {
        const float* W1l = msgW1 + (size_t)l * 261 * 128;
        hipMemsetAsync(agg, 0, 6400000 * sizeof(float), stream);
        if (sorted) {
            wprep_kernel<<<384, 256, 0, stream>>>(
                msgW2 + (size_t)l * 128 * 128, updW1 + (size_t)l * 256 * 128,
                updW2 + (size_t)l * 128 * 128, W1l, WP);
            projm_kernel<<<nblk_nodes, 256, 0, stream>>>(h, WP + 4 * 16384, WP + 5 * 16384, P);
            msgm_kernel<<<nblk_edges, 256, 0, stream>>>(P, srcP, dstP, eaP, d2,
                W1l + 256 * 128, msgb1 + l * 128, WP, msgb2 + l * 128, agg);
            updm_kernel<<<nblk_nodes, 256, 0, stream>>>(h, agg,
                WP + 1 * 16384, WP + 2 * 16384, WP + 3 * 16384,
                updb1 + l * 128, updb2 + l * 128, lng + l * 128, lnb + l * 128);
        } else {
            msgu_kernel<<<nblk_edges, 256, 0, stream>>>(h, srcI, dstI, eattr, d2,
                W1l, msgb1 + l * 128,
                msgW2 + (size_t)l * 128 * 128, msgb2 + l * 128, agg);
            updf_kernel<<<nblk_nodes, 256, 0, stream>>>(h, agg,
                updW1 + (size_t)l * 256 * 128, updb1 + l * 128,
                updW2 + (size_t)l * 128 * 128, updb2 + l * 128,
                lng + l * 128, lnb + l * 128);
        }
    }

    hipMemsetAsync(hsg, 0, 64500 * sizeof(float), stream);
    cnt_kernel<<<196, 256, 0, stream>>>(batch, cnt);
    pool_kernel<<<25000, 256, 0, stream>>>(h, batch, hsg);
    dec_kernel<<<1000, 256, 0, stream>>>(hsg, cnt, dW1, db1, dlng, dlnb,
                                         dW2, db2, dW3, db3, (float*)d_out);
}